// Round 1
// baseline (1489.449 us; speedup 1.0000x reference)
//
#include <hip/hip_runtime.h>
#include <hip/hip_bf16.h>
#include <math.h>

#define SCALE_ATTN 0.17677669529663687f  // 1/sqrt(32)

// ---------------- window |max-min| + eps ----------------
__global__ __launch_bounds__(256) void win_kernel(const float* __restrict__ G,
                                                  float* __restrict__ R, int total) {
    int i = blockIdx.x * 256 + threadIdx.x;
    if (i >= total) return;
    const float4* p = reinterpret_cast<const float4*>(G) + (size_t)i * 2;
    float4 a = p[0], b = p[1];
    float mx = fmaxf(fmaxf(fmaxf(a.x, a.y), fmaxf(a.z, a.w)),
                     fmaxf(fmaxf(b.x, b.y), fmaxf(b.z, b.w)));
    float mn = fminf(fminf(fminf(a.x, a.y), fminf(a.z, a.w)),
                     fminf(fminf(b.x, b.y), fminf(b.z, b.w)));
    R[i] = fabsf(mx - mn) + 1e-6f;
}

// ---------------- generic tiled fp32 GEMM ----------------
// C[m,n] = act( sum_k A[m,k]*B(k,n) + bias ) (+ residual)
// BL=0: B is [K,N] row-major;  BL=1: B is [N,K] row-major (i.e. X @ W^T)
// BIASMODE: 0 none, 1 per-n, 2 per-m.  ACT: 0 none, 1 relu, 2 exact gelu.
template <int BL, int BIASMODE, int ACT, bool RESID>
__global__ __launch_bounds__(256) void gemm_kernel(
    const float* __restrict__ A, const float* __restrict__ Bm,
    const float* __restrict__ bias, const float* __restrict__ Rres,
    float* __restrict__ C, int M, int N, int K,
    long sA, long sB, long sC) {
    A  += (long)blockIdx.z * sA;
    Bm += (long)blockIdx.z * sB;
    C  += (long)blockIdx.z * sC;
    __shared__ float As[64][17];
    __shared__ float Bs[16][65];
    int tid = threadIdx.x;
    int tx = tid & 15, ty = tid >> 4;
    int m0 = blockIdx.x * 64, n0 = blockIdx.y * 64;
    float acc[4][4] = {};
    for (int k0 = 0; k0 < K; k0 += 16) {
        #pragma unroll
        for (int i = 0; i < 4; i++) {
            int idx = tid + i * 256;
            As[idx >> 4][idx & 15] = A[(long)(m0 + (idx >> 4)) * K + k0 + (idx & 15)];
        }
        #pragma unroll
        for (int i = 0; i < 4; i++) {
            int idx = tid + i * 256;
            int bk = idx >> 6, bn = idx & 63;
            Bs[bk][bn] = (BL == 0) ? Bm[(long)(k0 + bk) * N + n0 + bn]
                                   : Bm[(long)(n0 + bn) * K + k0 + bk];
        }
        __syncthreads();
        #pragma unroll
        for (int kk = 0; kk < 16; kk++) {
            float ar[4], br[4];
            #pragma unroll
            for (int i = 0; i < 4; i++) ar[i] = As[ty * 4 + i][kk];
            #pragma unroll
            for (int j = 0; j < 4; j++) br[j] = Bs[kk][tx * 4 + j];
            #pragma unroll
            for (int i = 0; i < 4; i++)
                #pragma unroll
                for (int j = 0; j < 4; j++)
                    acc[i][j] = fmaf(ar[i], br[j], acc[i][j]);
        }
        __syncthreads();
    }
    const float* Rb = RESID ? (Rres + (long)blockIdx.z * sC) : nullptr;
    #pragma unroll
    for (int i = 0; i < 4; i++) {
        int m = m0 + ty * 4 + i;
        #pragma unroll
        for (int j = 0; j < 4; j++) {
            int n = n0 + tx * 4 + j;
            float v = acc[i][j];
            if (BIASMODE == 1) v += bias[n];
            if (BIASMODE == 2) v += bias[m];
            if (ACT == 1) v = fmaxf(v, 0.f);
            if (ACT == 2) v = 0.5f * v * (1.f + erff(v * 0.70710678118654752f));
            if (RESID) v += Rb[(long)m * N + n];
            C[(long)m * N + n] = v;
        }
    }
}

// ---------------- flash attention (fp32, one query per thread) ----------------
// Layouts: Q [B, L, 512], K/V [B, S, 512], head h at cols h*32..h*32+31.
template <int TS>
__global__ __launch_bounds__(256) void attn_kernel(
    const float* __restrict__ Q, const float* __restrict__ K,
    const float* __restrict__ V, float* __restrict__ O, int L, int S) {
    int bh = blockIdx.y;
    int b = bh >> 4;
    int h = bh & 15;
    int l = blockIdx.x * 256 + threadIdx.x;
    const float* qp = Q + ((long)b * L + l) * 512 + h * 32;
    float q[32];
    #pragma unroll
    for (int d = 0; d < 32; d++) q[d] = qp[d] * SCALE_ATTN;
    float m = -1e30f, lsum = 0.f;
    float acc[32] = {};
    __shared__ float Ks[TS][32], Vs[TS][32];
    const float* Kb = K + (long)b * S * 512 + h * 32;
    const float* Vb = V + (long)b * S * 512 + h * 32;
    for (int s0 = 0; s0 < S; s0 += TS) {
        __syncthreads();
        for (int i = threadIdx.x; i < TS * 32; i += 256) {
            int s = i >> 5, d = i & 31;
            Ks[s][d] = Kb[(long)(s0 + s) * 512 + d];
            Vs[s][d] = Vb[(long)(s0 + s) * 512 + d];
        }
        __syncthreads();
        float sc[TS];
        #pragma unroll
        for (int s = 0; s < TS; s++) {
            float a = 0.f;
            #pragma unroll
            for (int d = 0; d < 32; d++) a = fmaf(q[d], Ks[s][d], a);
            sc[s] = a;
        }
        float tmax = m;
        #pragma unroll
        for (int s = 0; s < TS; s++) tmax = fmaxf(tmax, sc[s]);
        float corr = __expf(m - tmax);
        m = tmax;
        lsum *= corr;
        #pragma unroll
        for (int d = 0; d < 32; d++) acc[d] *= corr;
        #pragma unroll
        for (int s = 0; s < TS; s++) {
            float p = __expf(sc[s] - m);
            lsum += p;
            #pragma unroll
            for (int d = 0; d < 32; d++) acc[d] = fmaf(p, Vs[s][d], acc[d]);
        }
    }
    float inv = 1.f / lsum;
    float* op = O + ((long)b * L + l) * 512 + h * 32;
    #pragma unroll
    for (int d = 0; d < 32; d++) op[d] = acc[d] * inv;
}

// ---------------- layernorm over 512, optional transposed store ----------------
template <bool TRANS>
__global__ __launch_bounds__(256) void ln_kernel(const float* __restrict__ X,
                                                 const float* __restrict__ g,
                                                 const float* __restrict__ bt,
                                                 float* __restrict__ Y) {
    int row = blockIdx.x;
    const float* xr = X + (long)row * 512;
    int t = threadIdx.x;
    float x0 = xr[t], x1 = xr[t + 256];
    float s = x0 + x1, ss = x0 * x0 + x1 * x1;
    #pragma unroll
    for (int off = 32; off > 0; off >>= 1) {
        s += __shfl_down(s, off);
        ss += __shfl_down(ss, off);
    }
    __shared__ float sred[4], ssred[4];
    int wid = t >> 6;
    if ((t & 63) == 0) { sred[wid] = s; ssred[wid] = ss; }
    __syncthreads();
    float ts = sred[0] + sred[1] + sred[2] + sred[3];
    float tss = ssred[0] + ssred[1] + ssred[2] + ssred[3];
    float mean = ts * (1.f / 512.f);
    float var = tss * (1.f / 512.f) - mean * mean;
    float rstd = rsqrtf(var + 1e-5f);
    float y0 = (x0 - mean) * rstd * g[t] + bt[t];
    float y1 = (x1 - mean) * rstd * g[t + 256] + bt[t + 256];
    if (TRANS) {
        int b = row >> 10, l = row & 1023;
        Y[((long)b * 512 + t) * 1024 + l] = y0;
        Y[((long)b * 512 + t + 256) * 1024 + l] = y1;
    } else {
        Y[(long)row * 512 + t] = y0;
        Y[(long)row * 512 + t + 256] = y1;
    }
}

extern "C" void kernel_launch(void* const* d_in, const int* in_sizes, int n_in,
                              void* d_out, int out_size, void* d_ws, size_t ws_size,
                              hipStream_t stream) {
    const float* x      = (const float*)d_in[0];
    const float* gfeat  = (const float*)d_in[1];
    const float* conv_w = (const float*)d_in[2];
    const float* conv_b = (const float*)d_in[3];
    const float* sa_wq = (const float*)d_in[4];
    const float* sa_bq = (const float*)d_in[5];
    const float* sa_wk = (const float*)d_in[6];
    const float* sa_bk = (const float*)d_in[7];
    const float* sa_wv = (const float*)d_in[8];
    const float* sa_bv = (const float*)d_in[9];
    const float* sa_wo = (const float*)d_in[10];
    const float* sa_bo = (const float*)d_in[11];
    const float* ca_wq = (const float*)d_in[12];
    const float* ca_bq = (const float*)d_in[13];
    const float* ca_wk = (const float*)d_in[14];
    const float* ca_bk = (const float*)d_in[15];
    const float* ca_wv = (const float*)d_in[16];
    const float* ca_bv = (const float*)d_in[17];
    const float* ca_wo = (const float*)d_in[18];
    const float* ca_bo = (const float*)d_in[19];
    const float* ffn_w1 = (const float*)d_in[20];
    const float* ffn_b1 = (const float*)d_in[21];
    const float* ffn_w2 = (const float*)d_in[22];
    const float* ffn_b2 = (const float*)d_in[23];
    const float* n1_g = (const float*)d_in[24];
    const float* n1_b = (const float*)d_in[25];
    const float* n2_g = (const float*)d_in[26];
    const float* n2_b = (const float*)d_in[27];
    const float* n3_g = (const float*)d_in[28];
    const float* n3_b = (const float*)d_in[29];

    float* W = (float*)d_ws;
    float* res   = W;                 // 1,048,576
    float* cross = res + 1048576;     // 1,048,576
    float* q     = cross + 1048576;   // 2,097,152
    float* k     = q + 2097152;       // 2,097,152
    float* v     = k + 2097152;       // 2,097,152
    float* att   = v + 2097152;       // 2,097,152
    float* h     = att + 2097152;     // 2,097,152
    float* hn    = h + 2097152;       // 2,097,152
    float* k2    = hn + 2097152;      // 1,048,576
    float* v2    = k2 + 1048576;      // 1,048,576
    float* mid   = v2 + 1048576;      // 8,388,608
    (void)ws_size; (void)n_in; (void)in_sizes; (void)out_size;

    // 1. window |max-min|+eps : gfeat [4,512,4096] -> res [4,512,512]
    win_kernel<<<4096, 256, 0, stream>>>(gfeat, res, 4 * 512 * 512);

    // 2. conv (k=1) + relu : cross[b] = relu(conv_w @ res[b] + conv_b), batched over b
    gemm_kernel<0, 2, 1, false><<<dim3(8, 8, 4), 256, 0, stream>>>(
        conv_w, res, conv_b, nullptr, cross, 512, 512, 512, 0, 262144, 262144);

    // 3. self-attn QKV projections: [4096,512] @ W^T
    gemm_kernel<1, 1, 0, false><<<dim3(64, 8, 1), 256, 0, stream>>>(
        x, sa_wq, sa_bq, nullptr, q, 4096, 512, 512, 0, 0, 0);
    gemm_kernel<1, 1, 0, false><<<dim3(64, 8, 1), 256, 0, stream>>>(
        x, sa_wk, sa_bk, nullptr, k, 4096, 512, 512, 0, 0, 0);
    gemm_kernel<1, 1, 0, false><<<dim3(64, 8, 1), 256, 0, stream>>>(
        x, sa_wv, sa_bv, nullptr, v, 4096, 512, 512, 0, 0, 0);

    // 4. self attention (S=1024)
    attn_kernel<32><<<dim3(4, 64), 256, 0, stream>>>(q, k, v, att, 1024, 1024);

    // 5. out proj + residual: h = att @ sa_wo^T + sa_bo + x
    gemm_kernel<1, 1, 0, true><<<dim3(64, 8, 1), 256, 0, stream>>>(
        att, sa_wo, sa_bo, x, h, 4096, 512, 512, 0, 0, 0);

    // 6. LN1: hn = LN(h)
    ln_kernel<false><<<4096, 256, 0, stream>>>(h, n1_g, n1_b, hn);

    // 7. cross-attn projections
    gemm_kernel<1, 1, 0, false><<<dim3(64, 8, 1), 256, 0, stream>>>(
        hn, ca_wq, ca_bq, nullptr, q, 4096, 512, 512, 0, 0, 0);
    gemm_kernel<1, 1, 0, false><<<dim3(32, 8, 1), 256, 0, stream>>>(
        cross, ca_wk, ca_bk, nullptr, k2, 2048, 512, 512, 0, 0, 0);
    gemm_kernel<1, 1, 0, false><<<dim3(32, 8, 1), 256, 0, stream>>>(
        cross, ca_wv, ca_bv, nullptr, v2, 2048, 512, 512, 0, 0, 0);

    // 8. cross attention (S=512)
    attn_kernel<32><<<dim3(4, 64), 256, 0, stream>>>(q, k2, v2, att, 1024, 512);

    // 9. out proj + residual: h = att @ ca_wo^T + ca_bo + hn
    gemm_kernel<1, 1, 0, true><<<dim3(64, 8, 1), 256, 0, stream>>>(
        att, ca_wo, ca_bo, hn, h, 4096, 512, 512, 0, 0, 0);

    // 10. LN2: hn = LN(h)
    ln_kernel<false><<<4096, 256, 0, stream>>>(h, n2_g, n2_b, hn);

    // 11. FFN up + exact gelu: mid = gelu(hn @ w1^T + b1)  [4096,2048]
    gemm_kernel<1, 1, 2, false><<<dim3(64, 32, 1), 256, 0, stream>>>(
        hn, ffn_w1, ffn_b1, nullptr, mid, 4096, 2048, 512, 0, 0, 0);

    // 12. FFN down + residual: h = mid @ w2^T + b2 + hn  [4096,512]
    gemm_kernel<1, 1, 0, true><<<dim3(64, 8, 1), 256, 0, stream>>>(
        mid, ffn_w2, ffn_b2, hn, h, 4096, 512, 2048, 0, 0, 0);

    // 13. LN3 + transpose to [B, 512, L]
    ln_kernel<true><<<4096, 256, 0, stream>>>(h, n3_g, n3_b, (float*)d_out);
}

// Round 2
// 1195.390 us; speedup vs baseline: 1.2460x; 1.2460x over previous
//
#include <hip/hip_runtime.h>
#include <hip/hip_bf16.h>
#include <math.h>

#define SCALE_ATTN 0.17677669529663687f  // 1/sqrt(32)

// ---------------- window |max-min| + eps ----------------
__global__ __launch_bounds__(256) void win_kernel(const float* __restrict__ G,
                                                  float* __restrict__ R, int total) {
    int i = blockIdx.x * 256 + threadIdx.x;
    if (i >= total) return;
    const float4* p = reinterpret_cast<const float4*>(G) + (size_t)i * 2;
    float4 a = p[0], b = p[1];
    float mx = fmaxf(fmaxf(fmaxf(a.x, a.y), fmaxf(a.z, a.w)),
                     fmaxf(fmaxf(b.x, b.y), fmaxf(b.z, b.w)));
    float mn = fminf(fminf(fminf(a.x, a.y), fminf(a.z, a.w)),
                     fminf(fminf(b.x, b.y), fminf(b.z, b.w)));
    R[i] = fabsf(mx - mn) + 1e-6f;
}

// ---------------- generic tiled fp32 GEMM ----------------
// C[m,n] = act( sum_k A[m,k]*B(k,n) + bias ) (+ residual)
// BL=0: B is [K,N] row-major;  BL=1: B is [N,K] row-major (i.e. X @ W^T)
// BIASMODE: 0 none, 1 per-n, 2 per-m.  ACT: 0 none, 1 relu, 2 exact gelu.
template <int BL, int BIASMODE, int ACT, bool RESID>
__global__ __launch_bounds__(256) void gemm_kernel(
    const float* __restrict__ A, const float* __restrict__ Bm,
    const float* __restrict__ bias, const float* __restrict__ Rres,
    float* __restrict__ C, int M, int N, int K,
    long sA, long sB, long sC) {
    A  += (long)blockIdx.z * sA;
    Bm += (long)blockIdx.z * sB;
    C  += (long)blockIdx.z * sC;
    __shared__ float As[64][17];
    __shared__ float Bs[16][65];
    int tid = threadIdx.x;
    int tx = tid & 15, ty = tid >> 4;
    int m0 = blockIdx.x * 64, n0 = blockIdx.y * 64;
    float acc[4][4] = {};
    for (int k0 = 0; k0 < K; k0 += 16) {
        #pragma unroll
        for (int i = 0; i < 4; i++) {
            int idx = tid + i * 256;
            As[idx >> 4][idx & 15] = A[(long)(m0 + (idx >> 4)) * K + k0 + (idx & 15)];
        }
        #pragma unroll
        for (int i = 0; i < 4; i++) {
            int idx = tid + i * 256;
            int bk = idx >> 6, bn = idx & 63;
            Bs[bk][bn] = (BL == 0) ? Bm[(long)(k0 + bk) * N + n0 + bn]
                                   : Bm[(long)(n0 + bn) * K + k0 + bk];
        }
        __syncthreads();
        #pragma unroll
        for (int kk = 0; kk < 16; kk++) {
            float ar[4], br[4];
            #pragma unroll
            for (int i = 0; i < 4; i++) ar[i] = As[ty * 4 + i][kk];
            #pragma unroll
            for (int j = 0; j < 4; j++) br[j] = Bs[kk][tx * 4 + j];
            #pragma unroll
            for (int i = 0; i < 4; i++)
                #pragma unroll
                for (int j = 0; j < 4; j++)
                    acc[i][j] = fmaf(ar[i], br[j], acc[i][j]);
        }
        __syncthreads();
    }
    const float* Rb = RESID ? (Rres + (long)blockIdx.z * sC) : nullptr;
    #pragma unroll
    for (int i = 0; i < 4; i++) {
        int m = m0 + ty * 4 + i;
        #pragma unroll
        for (int j = 0; j < 4; j++) {
            int n = n0 + tx * 4 + j;
            float v = acc[i][j];
            if (BIASMODE == 1) v += bias[n];
            if (BIASMODE == 2) v += bias[m];
            if (ACT == 1) v = fmaxf(v, 0.f);
            if (ACT == 2) v = 0.5f * v * (1.f + erff(v * 0.70710678118654752f));
            if (RESID) v += Rb[(long)m * N + n];
            C[(long)m * N + n] = v;
        }
    }
}

// ---------------- flash attention pass 1: partial (m, sum, acc) per S-chunk ----------------
// One query per thread. blockIdx.z = S-chunk index. Unnormalized partials out.
// Pacc[(z*NQ + qid)*32 + d] = sum_s p*V ; Pml[(z*NQ+qid)*2 + {0,1}] = {m, sum_p}
template <int TS>
__global__ __launch_bounds__(256) void attn_part_kernel(
    const float* __restrict__ Q, const float* __restrict__ K,
    const float* __restrict__ V, float* __restrict__ Pacc,
    float* __restrict__ Pml, int L, int S, int chunk, int NQ) {
    int bh = blockIdx.y;
    int b = bh >> 4;
    int h = bh & 15;
    int l = blockIdx.x * 256 + threadIdx.x;
    int z = blockIdx.z;
    const float* qp = Q + ((long)b * L + l) * 512 + h * 32;
    float q[32];
    #pragma unroll
    for (int d = 0; d < 32; d++) q[d] = qp[d] * SCALE_ATTN;
    float m = -1e30f, lsum = 0.f;
    float acc[32] = {};
    __shared__ float Ks[TS][32], Vs[TS][32];
    const float* Kb = K + (long)b * S * 512 + h * 32;
    const float* Vb = V + (long)b * S * 512 + h * 32;
    int sbeg = z * chunk, send = sbeg + chunk;
    for (int s0 = sbeg; s0 < send; s0 += TS) {
        __syncthreads();
        for (int i = threadIdx.x; i < TS * 32; i += 256) {
            int s = i >> 5, d = i & 31;
            Ks[s][d] = Kb[(long)(s0 + s) * 512 + d];
            Vs[s][d] = Vb[(long)(s0 + s) * 512 + d];
        }
        __syncthreads();
        float sc[TS];
        #pragma unroll
        for (int s = 0; s < TS; s++) {
            float a = 0.f;
            #pragma unroll
            for (int d = 0; d < 32; d++) a = fmaf(q[d], Ks[s][d], a);
            sc[s] = a;
        }
        float tmax = m;
        #pragma unroll
        for (int s = 0; s < TS; s++) tmax = fmaxf(tmax, sc[s]);
        float corr = __expf(m - tmax);
        m = tmax;
        lsum *= corr;
        #pragma unroll
        for (int d = 0; d < 32; d++) acc[d] *= corr;
        #pragma unroll
        for (int s = 0; s < TS; s++) {
            float p = __expf(sc[s] - m);
            lsum += p;
            #pragma unroll
            for (int d = 0; d < 32; d++) acc[d] = fmaf(p, Vs[s][d], acc[d]);
        }
    }
    int qid = bh * L + l;
    float* pa = Pacc + ((long)z * NQ + qid) * 32;
    #pragma unroll
    for (int d = 0; d < 32; d++) pa[d] = acc[d];
    Pml[((long)z * NQ + qid) * 2 + 0] = m;
    Pml[((long)z * NQ + qid) * 2 + 1] = lsum;
}

// ---------------- flash attention pass 2: combine NSPLIT partials ----------------
template <int NSPLIT>
__global__ __launch_bounds__(256) void attn_combine_kernel(
    const float* __restrict__ Pacc, const float* __restrict__ Pml,
    float* __restrict__ O, int L, int NQ) {
    int qid = blockIdx.x * 256 + threadIdx.x;
    if (qid >= NQ) return;
    float mv[NSPLIT], lv[NSPLIT];
    float mstar = -1e30f;
    #pragma unroll
    for (int z = 0; z < NSPLIT; z++) {
        mv[z] = Pml[((long)z * NQ + qid) * 2 + 0];
        lv[z] = Pml[((long)z * NQ + qid) * 2 + 1];
        mstar = fmaxf(mstar, mv[z]);
    }
    float w[NSPLIT];
    float wsum = 0.f;
    #pragma unroll
    for (int z = 0; z < NSPLIT; z++) {
        w[z] = __expf(mv[z] - mstar);
        wsum += w[z] * lv[z];
    }
    float inv = 1.f / wsum;
    int bh = qid / L;
    int l = qid - bh * L;
    int b = bh >> 4, h = bh & 15;
    float* op = O + ((long)b * L + l) * 512 + h * 32;
    #pragma unroll
    for (int d = 0; d < 32; d++) {
        float s = 0.f;
        #pragma unroll
        for (int z = 0; z < NSPLIT; z++)
            s = fmaf(w[z], Pacc[((long)z * NQ + qid) * 32 + d], s);
        op[d] = s * inv;
    }
}

// ---------------- layernorm over 512, optional transposed store ----------------
template <bool TRANS>
__global__ __launch_bounds__(256) void ln_kernel(const float* __restrict__ X,
                                                 const float* __restrict__ g,
                                                 const float* __restrict__ bt,
                                                 float* __restrict__ Y) {
    int row = blockIdx.x;
    const float* xr = X + (long)row * 512;
    int t = threadIdx.x;
    float x0 = xr[t], x1 = xr[t + 256];
    float s = x0 + x1, ss = x0 * x0 + x1 * x1;
    #pragma unroll
    for (int off = 32; off > 0; off >>= 1) {
        s += __shfl_down(s, off);
        ss += __shfl_down(ss, off);
    }
    __shared__ float sred[4], ssred[4];
    int wid = t >> 6;
    if ((t & 63) == 0) { sred[wid] = s; ssred[wid] = ss; }
    __syncthreads();
    float ts = sred[0] + sred[1] + sred[2] + sred[3];
    float tss = ssred[0] + ssred[1] + ssred[2] + ssred[3];
    float mean = ts * (1.f / 512.f);
    float var = tss * (1.f / 512.f) - mean * mean;
    float rstd = rsqrtf(var + 1e-5f);
    float y0 = (x0 - mean) * rstd * g[t] + bt[t];
    float y1 = (x1 - mean) * rstd * g[t + 256] + bt[t + 256];
    if (TRANS) {
        int b = row >> 10, l = row & 1023;
        Y[((long)b * 512 + t) * 1024 + l] = y0;
        Y[((long)b * 512 + t + 256) * 1024 + l] = y1;
    } else {
        Y[(long)row * 512 + t] = y0;
        Y[(long)row * 512 + t + 256] = y1;
    }
}

extern "C" void kernel_launch(void* const* d_in, const int* in_sizes, int n_in,
                              void* d_out, int out_size, void* d_ws, size_t ws_size,
                              hipStream_t stream) {
    const float* x      = (const float*)d_in[0];
    const float* gfeat  = (const float*)d_in[1];
    const float* conv_w = (const float*)d_in[2];
    const float* conv_b = (const float*)d_in[3];
    const float* sa_wq = (const float*)d_in[4];
    const float* sa_bq = (const float*)d_in[5];
    const float* sa_wk = (const float*)d_in[6];
    const float* sa_bk = (const float*)d_in[7];
    const float* sa_wv = (const float*)d_in[8];
    const float* sa_bv = (const float*)d_in[9];
    const float* sa_wo = (const float*)d_in[10];
    const float* sa_bo = (const float*)d_in[11];
    const float* ca_wq = (const float*)d_in[12];
    const float* ca_bq = (const float*)d_in[13];
    const float* ca_wk = (const float*)d_in[14];
    const float* ca_bk = (const float*)d_in[15];
    const float* ca_wv = (const float*)d_in[16];
    const float* ca_bv = (const float*)d_in[17];
    const float* ca_wo = (const float*)d_in[18];
    const float* ca_bo = (const float*)d_in[19];
    const float* ffn_w1 = (const float*)d_in[20];
    const float* ffn_b1 = (const float*)d_in[21];
    const float* ffn_w2 = (const float*)d_in[22];
    const float* ffn_b2 = (const float*)d_in[23];
    const float* n1_g = (const float*)d_in[24];
    const float* n1_b = (const float*)d_in[25];
    const float* n2_g = (const float*)d_in[26];
    const float* n2_b = (const float*)d_in[27];
    const float* n3_g = (const float*)d_in[28];
    const float* n3_b = (const float*)d_in[29];

    float* W = (float*)d_ws;
    float* res   = W;                 // 1,048,576  (win out; later attn Pml)
    float* cross = res + 1048576;     // 1,048,576
    float* q     = cross + 1048576;   // 2,097,152
    float* k     = q + 2097152;       // 2,097,152
    float* v     = k + 2097152;       // 2,097,152
    float* att   = v + 2097152;       // 2,097,152
    float* h     = att + 2097152;     // 2,097,152
    float* hn    = h + 2097152;       // 2,097,152
    float* k2    = hn + 2097152;      // 1,048,576
    float* v2    = k2 + 1048576;      // 1,048,576
    float* mid   = v2 + 1048576;      // 8,388,608 (FFN mid; earlier attn Pacc)
    (void)ws_size; (void)n_in; (void)in_sizes; (void)out_size;

    const int NQ = 4 * 16 * 1024;  // 65536 queries

    // 1. window |max-min|+eps : gfeat [4,512,4096] -> res [4,512,512]
    win_kernel<<<4096, 256, 0, stream>>>(gfeat, res, 4 * 512 * 512);

    // 2. conv (k=1) + relu : cross[b] = relu(conv_w @ res[b] + conv_b)
    gemm_kernel<0, 2, 1, false><<<dim3(8, 8, 4), 256, 0, stream>>>(
        conv_w, res, conv_b, nullptr, cross, 512, 512, 512, 0, 262144, 262144);

    // 3. self-attn QKV projections: [4096,512] @ W^T
    gemm_kernel<1, 1, 0, false><<<dim3(64, 8, 1), 256, 0, stream>>>(
        x, sa_wq, sa_bq, nullptr, q, 4096, 512, 512, 0, 0, 0);
    gemm_kernel<1, 1, 0, false><<<dim3(64, 8, 1), 256, 0, stream>>>(
        x, sa_wk, sa_bk, nullptr, k, 4096, 512, 512, 0, 0, 0);
    gemm_kernel<1, 1, 0, false><<<dim3(64, 8, 1), 256, 0, stream>>>(
        x, sa_wv, sa_bv, nullptr, v, 4096, 512, 512, 0, 0, 0);

    // 4. self attention (S=1024), split-KV flash: 4 chunks of 256 + combine
    attn_part_kernel<32><<<dim3(4, 64, 4), 256, 0, stream>>>(
        q, k, v, mid, res, 1024, 1024, 256, NQ);
    attn_combine_kernel<4><<<NQ / 256, 256, 0, stream>>>(mid, res, att, 1024, NQ);

    // 5. out proj + residual: h = att @ sa_wo^T + sa_bo + x
    gemm_kernel<1, 1, 0, true><<<dim3(64, 8, 1), 256, 0, stream>>>(
        att, sa_wo, sa_bo, x, h, 4096, 512, 512, 0, 0, 0);

    // 6. LN1: hn = LN(h)
    ln_kernel<false><<<4096, 256, 0, stream>>>(h, n1_g, n1_b, hn);

    // 7. cross-attn projections
    gemm_kernel<1, 1, 0, false><<<dim3(64, 8, 1), 256, 0, stream>>>(
        hn, ca_wq, ca_bq, nullptr, q, 4096, 512, 512, 0, 0, 0);
    gemm_kernel<1, 1, 0, false><<<dim3(32, 8, 1), 256, 0, stream>>>(
        cross, ca_wk, ca_bk, nullptr, k2, 2048, 512, 512, 0, 0, 0);
    gemm_kernel<1, 1, 0, false><<<dim3(32, 8, 1), 256, 0, stream>>>(
        cross, ca_wv, ca_bv, nullptr, v2, 2048, 512, 512, 0, 0, 0);

    // 8. cross attention (S=512), split-KV flash: 4 chunks of 128 + combine
    attn_part_kernel<32><<<dim3(4, 64, 4), 256, 0, stream>>>(
        q, k2, v2, mid, res, 1024, 512, 128, NQ);
    attn_combine_kernel<4><<<NQ / 256, 256, 0, stream>>>(mid, res, att, 1024, NQ);

    // 9. out proj + residual: h = att @ ca_wo^T + ca_bo + hn
    gemm_kernel<1, 1, 0, true><<<dim3(64, 8, 1), 256, 0, stream>>>(
        att, ca_wo, ca_bo, hn, h, 4096, 512, 512, 0, 0, 0);

    // 10. LN2: hn = LN(h)
    ln_kernel<false><<<4096, 256, 0, stream>>>(h, n2_g, n2_b, hn);

    // 11. FFN up + exact gelu: mid = gelu(hn @ w1^T + b1)  [4096,2048]
    gemm_kernel<1, 1, 2, false><<<dim3(64, 32, 1), 256, 0, stream>>>(
        hn, ffn_w1, ffn_b1, nullptr, mid, 4096, 2048, 512, 0, 0, 0);

    // 12. FFN down + residual: h = mid @ w2^T + b2 + hn  [4096,512]
    gemm_kernel<1, 1, 0, true><<<dim3(64, 8, 1), 256, 0, stream>>>(
        mid, ffn_w2, ffn_b2, hn, h, 4096, 512, 2048, 0, 0, 0);

    // 13. LN3 + transpose to [B, 512, L]
    ln_kernel<true><<<4096, 256, 0, stream>>>(h, n3_g, n3_b, (float*)d_out);
}

// Round 3
// 504.469 us; speedup vs baseline: 2.9525x; 2.3696x over previous
//
#include <hip/hip_runtime.h>
#include <hip/hip_bf16.h>
#include <math.h>

#define SCALE_ATTN 0.17677669529663687f  // 1/sqrt(32)

typedef unsigned short u16;
typedef __attribute__((ext_vector_type(8))) short bshort8;
typedef __attribute__((ext_vector_type(4))) float f32x4;

__device__ inline u16 f2b(float f) {  // fp32 -> bf16 RNE
    union { float f; uint32_t u; } c;
    c.f = f;
    uint32_t u = c.u;
    return (u16)((u + 0x7fffu + ((u >> 16) & 1u)) >> 16);
}

__device__ inline void gload_lds16(const void* g, void* lds) {
    __builtin_amdgcn_global_load_lds(
        (const __attribute__((address_space(1))) void*)g,
        (__attribute__((address_space(3))) void*)lds, 16, 0, 0);
}

// ---------------- batched fp32->bf16 convert (11 weights + x) ----------------
struct WSrc { const float* p[12]; };
__global__ __launch_bounds__(256) void wconv_kernel(WSrc s, u16* __restrict__ dst) {
    long e = ((long)blockIdx.x * 256 + threadIdx.x) * 4;
    if (e >= 6553600) return;
    int w; long base;
    if (e < 2359296)      { w = (int)(e >> 18); base = (long)w << 18; }
    else if (e < 3407872) { w = 9;  base = 2359296; }
    else if (e < 4456448) { w = 10; base = 3407872; }
    else                  { w = 11; base = 4456448; }
    float4 v = *(const float4*)(s.p[w] + (e - base));
    dst[e + 0] = f2b(v.x); dst[e + 1] = f2b(v.y);
    dst[e + 2] = f2b(v.z); dst[e + 3] = f2b(v.w);
}

// ---------------- window |max-min| + eps -> transposed bf16 [b][n][c] ----------------
__global__ __launch_bounds__(256) void win_kernel(const float* __restrict__ G,
                                                  u16* __restrict__ Rt, int total) {
    int i = blockIdx.x * 256 + threadIdx.x;
    if (i >= total) return;
    const float4* p = reinterpret_cast<const float4*>(G) + (size_t)i * 2;
    float4 a = p[0], b = p[1];
    float mx = fmaxf(fmaxf(fmaxf(a.x, a.y), fmaxf(a.z, a.w)),
                     fmaxf(fmaxf(b.x, b.y), fmaxf(b.z, b.w)));
    float mn = fminf(fminf(fminf(a.x, a.y), fminf(a.z, a.w)),
                     fminf(fminf(b.x, b.y), fminf(b.z, b.w)));
    int b_ = i >> 18, c = (i >> 9) & 511, n = i & 511;
    Rt[((long)(b_ * 512 + n) << 9) + c] = f2b(fabsf(mx - mn) + 1e-6f);
}

// ---------------- bf16 MFMA GEMM: C[m,n] = act(sum_k A[m,k]*Bt[n,k] + bias) (+resid) ----
// A [M,K] bf16 row-major, Bt [N,K] bf16 row-major. 64x64 tile, BK=64, 4 waves.
// LDS XOR-swizzle: stored[row][bo] = src[row][bo ^ ((row&7)<<4)]  (linear dest,
// inverse-swizzled global source, swizzled read — rule #21).
template <int BIASMODE, int ACT, bool RESID, bool OUTBF>
__global__ __launch_bounds__(256) void bgemm_kernel(
    const u16* __restrict__ A, const u16* __restrict__ Bt,
    const float* __restrict__ bias, const float* __restrict__ Rres,
    void* __restrict__ Cout, int M, int N, int K,
    long sA, long sB, long sC) {
    A  += (long)blockIdx.z * sA;
    Bt += (long)blockIdx.z * sB;
    __shared__ u16 As[64 * 64];
    __shared__ u16 Bs[64 * 64];
    int tid = threadIdx.x;
    int lane = tid & 63, wv = tid >> 6;
    int wr = wv >> 1, wc = wv & 1;
    int m0 = blockIdx.x * 64, n0 = blockIdx.y * 64;
    f32x4 acc[2][2] = {};
    int srow = lane >> 3;                               // row-within-8 for staging
    int sbo = ((lane & 7) << 4) ^ (srow << 4);          // pre-swizzled source byte off
    int selem = sbo >> 1;
    for (int k0 = 0; k0 < K; k0 += 64) {
        #pragma unroll
        for (int i = 0; i < 2; i++) {
            int r = i * 32 + wv * 8 + srow;
            gload_lds16(A + (long)(m0 + r) * K + k0 + selem,
                        (char*)As + (i * 32 + wv * 8) * 128);
            gload_lds16(Bt + (long)(n0 + r) * K + k0 + selem,
                        (char*)Bs + (i * 32 + wv * 8) * 128);
        }
        __syncthreads();
        #pragma unroll
        for (int ks = 0; ks < 2; ks++) {
            bshort8 af[2], bf[2];
            int kbo = ks * 64 + ((lane >> 4) << 4);
            #pragma unroll
            for (int f = 0; f < 2; f++) {
                int arow = wr * 32 + f * 16 + (lane & 15);
                af[f] = *(const bshort8*)((const char*)As + arow * 128 +
                                          (kbo ^ ((arow & 7) << 4)));
                int brow = wc * 32 + f * 16 + (lane & 15);
                bf[f] = *(const bshort8*)((const char*)Bs + brow * 128 +
                                          (kbo ^ ((brow & 7) << 4)));
            }
            #pragma unroll
            for (int fi = 0; fi < 2; fi++)
                #pragma unroll
                for (int fj = 0; fj < 2; fj++)
                    acc[fi][fj] = __builtin_amdgcn_mfma_f32_16x16x32_bf16(
                        af[fi], bf[fj], acc[fi][fj], 0, 0, 0);
        }
        __syncthreads();
    }
    #pragma unroll
    for (int fi = 0; fi < 2; fi++)
        #pragma unroll
        for (int fj = 0; fj < 2; fj++)
            #pragma unroll
            for (int r = 0; r < 4; r++) {
                int row = m0 + wr * 32 + fi * 16 + ((lane >> 4) << 2) + r;
                int col = n0 + wc * 32 + fj * 16 + (lane & 15);
                float v = acc[fi][fj][r];
                if (BIASMODE == 1) v += bias[col];
                if (BIASMODE == 2) v += bias[row];
                if (ACT == 1) v = fmaxf(v, 0.f);
                if (ACT == 2) v = 0.5f * v * (1.f + erff(v * 0.70710678118654752f));
                if (RESID) v += Rres[(long)row * N + col];
                long off = (long)blockIdx.z * sC + (long)row * N + col;
                if (OUTBF) ((u16*)Cout)[off] = f2b(v);
                else       ((float*)Cout)[off] = v;
            }
}

// ---------------- flash attention pass 1 (fp32, one query/thread, S-split) ----------
template <int TS>
__global__ __launch_bounds__(256) void attn_part_kernel(
    const float* __restrict__ Q, const float* __restrict__ K,
    const float* __restrict__ V, float* __restrict__ Pacc,
    float* __restrict__ Pml, int L, int S, int chunk, int NQ) {
    int bh = blockIdx.y;
    int b = bh >> 4;
    int h = bh & 15;
    int l = blockIdx.x * 256 + threadIdx.x;
    int z = blockIdx.z;
    const float* qp = Q + ((long)b * L + l) * 512 + h * 32;
    float q[32];
    #pragma unroll
    for (int d = 0; d < 32; d++) q[d] = qp[d] * SCALE_ATTN;
    float m = -1e30f, lsum = 0.f;
    float acc[32] = {};
    __shared__ float Ks[TS][32], Vs[TS][32];
    const float* Kb = K + (long)b * S * 512 + h * 32;
    const float* Vb = V + (long)b * S * 512 + h * 32;
    int sbeg = z * chunk, send = sbeg + chunk;
    for (int s0 = sbeg; s0 < send; s0 += TS) {
        __syncthreads();
        for (int i = threadIdx.x; i < TS * 32; i += 256) {
            int s = i >> 5, d = i & 31;
            Ks[s][d] = Kb[(long)(s0 + s) * 512 + d];
            Vs[s][d] = Vb[(long)(s0 + s) * 512 + d];
        }
        __syncthreads();
        float sc[TS];
        #pragma unroll
        for (int s = 0; s < TS; s++) {
            float a = 0.f;
            #pragma unroll
            for (int d = 0; d < 32; d++) a = fmaf(q[d], Ks[s][d], a);
            sc[s] = a;
        }
        float tmax = m;
        #pragma unroll
        for (int s = 0; s < TS; s++) tmax = fmaxf(tmax, sc[s]);
        float corr = __expf(m - tmax);
        m = tmax;
        lsum *= corr;
        #pragma unroll
        for (int d = 0; d < 32; d++) acc[d] *= corr;
        #pragma unroll
        for (int s = 0; s < TS; s++) {
            float p = __expf(sc[s] - m);
            lsum += p;
            #pragma unroll
            for (int d = 0; d < 32; d++) acc[d] = fmaf(p, Vs[s][d], acc[d]);
        }
    }
    int qid = bh * L + l;
    float* pa = Pacc + ((long)z * NQ + qid) * 32;
    #pragma unroll
    for (int d = 0; d < 32; d++) pa[d] = acc[d];
    Pml[((long)z * NQ + qid) * 2 + 0] = m;
    Pml[((long)z * NQ + qid) * 2 + 1] = lsum;
}

// ---------------- flash attention pass 2: combine -> bf16 output ----------------
template <int NSPLIT>
__global__ __launch_bounds__(256) void attn_combine_kernel(
    const float* __restrict__ Pacc, const float* __restrict__ Pml,
    u16* __restrict__ O, int L, int NQ) {
    int qid = blockIdx.x * 256 + threadIdx.x;
    if (qid >= NQ) return;
    float mv[NSPLIT], lv[NSPLIT];
    float mstar = -1e30f;
    #pragma unroll
    for (int z = 0; z < NSPLIT; z++) {
        mv[z] = Pml[((long)z * NQ + qid) * 2 + 0];
        lv[z] = Pml[((long)z * NQ + qid) * 2 + 1];
        mstar = fmaxf(mstar, mv[z]);
    }
    float w[NSPLIT];
    float wsum = 0.f;
    #pragma unroll
    for (int z = 0; z < NSPLIT; z++) {
        w[z] = __expf(mv[z] - mstar);
        wsum += w[z] * lv[z];
    }
    float inv = 1.f / wsum;
    int bh = qid / L;
    int l = qid - bh * L;
    int b = bh >> 4, h = bh & 15;
    u16* op = O + ((long)b * L + l) * 512 + h * 32;
    #pragma unroll
    for (int d = 0; d < 32; d++) {
        float s = 0.f;
        #pragma unroll
        for (int z = 0; z < NSPLIT; z++)
            s = fmaf(w[z], Pacc[((long)z * NQ + qid) * 32 + d], s);
        op[d] = f2b(s * inv);
    }
}

// ---------------- layernorm over 512; optional bf16 dual-store / transposed out ------
template <bool TRANS, bool DUAL>
__global__ __launch_bounds__(256) void ln_kernel(const float* __restrict__ X,
                                                 const float* __restrict__ g,
                                                 const float* __restrict__ bt,
                                                 float* __restrict__ Y,
                                                 u16* __restrict__ Yb) {
    int row = blockIdx.x;
    const float* xr = X + (long)row * 512;
    int t = threadIdx.x;
    float x0 = xr[t], x1 = xr[t + 256];
    float s = x0 + x1, ss = x0 * x0 + x1 * x1;
    #pragma unroll
    for (int off = 32; off > 0; off >>= 1) {
        s += __shfl_down(s, off);
        ss += __shfl_down(ss, off);
    }
    __shared__ float sred[4], ssred[4];
    int wid = t >> 6;
    if ((t & 63) == 0) { sred[wid] = s; ssred[wid] = ss; }
    __syncthreads();
    float ts = sred[0] + sred[1] + sred[2] + sred[3];
    float tss = ssred[0] + ssred[1] + ssred[2] + ssred[3];
    float mean = ts * (1.f / 512.f);
    float var = tss * (1.f / 512.f) - mean * mean;
    float rstd = rsqrtf(var + 1e-5f);
    float y0 = (x0 - mean) * rstd * g[t] + bt[t];
    float y1 = (x1 - mean) * rstd * g[t + 256] + bt[t + 256];
    if (TRANS) {
        int b = row >> 10, l = row & 1023;
        Y[((long)b * 512 + t) * 1024 + l] = y0;
        Y[((long)b * 512 + t + 256) * 1024 + l] = y1;
    } else {
        Y[(long)row * 512 + t] = y0;
        Y[(long)row * 512 + t + 256] = y1;
    }
    if (DUAL) {
        Yb[(long)row * 512 + t] = f2b(y0);
        Yb[(long)row * 512 + t + 256] = f2b(y1);
    }
}

extern "C" void kernel_launch(void* const* d_in, const int* in_sizes, int n_in,
                              void* d_out, int out_size, void* d_ws, size_t ws_size,
                              hipStream_t stream) {
    const float* x      = (const float*)d_in[0];
    const float* gfeat  = (const float*)d_in[1];
    const float* conv_w = (const float*)d_in[2];
    const float* conv_b = (const float*)d_in[3];
    const float* sa_wq = (const float*)d_in[4];
    const float* sa_bq = (const float*)d_in[5];
    const float* sa_wk = (const float*)d_in[6];
    const float* sa_bk = (const float*)d_in[7];
    const float* sa_wv = (const float*)d_in[8];
    const float* sa_bv = (const float*)d_in[9];
    const float* sa_wo = (const float*)d_in[10];
    const float* sa_bo = (const float*)d_in[11];
    const float* ca_wq = (const float*)d_in[12];
    const float* ca_bq = (const float*)d_in[13];
    const float* ca_wk = (const float*)d_in[14];
    const float* ca_bk = (const float*)d_in[15];
    const float* ca_wv = (const float*)d_in[16];
    const float* ca_bv = (const float*)d_in[17];
    const float* ca_wo = (const float*)d_in[18];
    const float* ca_bo = (const float*)d_in[19];
    const float* ffn_w1 = (const float*)d_in[20];
    const float* ffn_b1 = (const float*)d_in[21];
    const float* ffn_w2 = (const float*)d_in[22];
    const float* ffn_b2 = (const float*)d_in[23];
    const float* n1_g = (const float*)d_in[24];
    const float* n1_b = (const float*)d_in[25];
    const float* n2_g = (const float*)d_in[26];
    const float* n2_b = (const float*)d_in[27];
    const float* n3_g = (const float*)d_in[28];
    const float* n3_b = (const float*)d_in[29];
    (void)ws_size; (void)n_in; (void)in_sizes; (void)out_size;

    const long M_ = 1048576;
    float* W0 = (float*)d_ws;
    float* q    = W0;                       // [0,  2M)  fp32
    float* k    = W0 + 2 * M_;              // [2M, 4M)  fp32
    float* v    = W0 + 4 * M_;              // [4M, 6M)  fp32
    float* h    = W0 + 6 * M_;              // [6M, 8M)  fp32
    u16*   midb = (u16*)(W0 + 8 * M_);      // [8M, 12M) 8M bf16
    float* hn   = W0 + 12 * M_;             // [12M,14M) fp32
    u16*   hnb  = (u16*)(W0 + 14 * M_);     // [14M,15M) 2M bf16
    u16*   attb = (u16*)(W0 + 15 * M_);     // [15M,16M) 2M bf16
    float* k2   = W0 + 16 * M_;             // [16M,17M) fp32
    float* v2   = W0 + 17 * M_;             // [17M,18M) fp32
    u16*   wsb  = (u16*)(W0 + 18 * M_);     // [18M,~21.2M) 6,553,600 bf16
    u16*   res_tb = (u16*)(W0 + 22 * M_);   // [22M,22.5M) 1M bf16
    u16*   crossb = (u16*)(W0 + 23 * M_);   // [23M,23.5M) 1M bf16
    // attn partial overlays (dead regions at those points in the stream):
    float* selfPacc = h;             // 8M fp32 over h+midb+hn
    float* selfPml  = W0 + 14 * M_;  // 0.5M fp32 over hnb
    float* crossPacc = k;            // 8M fp32 over k+v+h+half of midb
    float* crossPml  = W0 + 10 * M_; // 0.5M fp32 inside midb

    const u16* conv_wb = wsb;
    const u16* sa_wqb = wsb + 262144, *sa_wkb = wsb + 524288;
    const u16* sa_wvb = wsb + 786432, *sa_wob = wsb + 1048576;
    const u16* ca_wqb = wsb + 1310720, *ca_wkb = wsb + 1572864;
    const u16* ca_wvb = wsb + 1835008, *ca_wob = wsb + 2097152;
    const u16* ffn1b = wsb + 2359296, *ffn2b = wsb + 3407872;
    const u16* xb = wsb + 4456448;

    const int NQ = 65536;

    // 0. convert weights + x to bf16 (one batched kernel)
    WSrc ws;
    ws.p[0] = conv_w; ws.p[1] = sa_wq; ws.p[2] = sa_wk; ws.p[3] = sa_wv;
    ws.p[4] = sa_wo; ws.p[5] = ca_wq; ws.p[6] = ca_wk; ws.p[7] = ca_wv;
    ws.p[8] = ca_wo; ws.p[9] = ffn_w1; ws.p[10] = ffn_w2; ws.p[11] = x;
    wconv_kernel<<<6400, 256, 0, stream>>>(ws, wsb);

    // 1. window |max-min|+eps, transposed bf16: res_tb [b][n][c]
    win_kernel<<<4096, 256, 0, stream>>>(gfeat, res_tb, 4 * 512 * 512);

    // 2. conv+relu: crossb[b][o,n] = relu(conv_w @ res_t[b]^T + conv_b[o])
    bgemm_kernel<2, 1, false, true><<<dim3(8, 8, 4), 256, 0, stream>>>(
        conv_wb, res_tb, conv_b, nullptr, crossb, 512, 512, 512, 0, 262144, 262144);

    // 3. self-attn QKV projections -> fp32
    bgemm_kernel<1, 0, false, false><<<dim3(64, 8, 1), 256, 0, stream>>>(
        xb, sa_wqb, sa_bq, nullptr, q, 4096, 512, 512, 0, 0, 0);
    bgemm_kernel<1, 0, false, false><<<dim3(64, 8, 1), 256, 0, stream>>>(
        xb, sa_wkb, sa_bk, nullptr, k, 4096, 512, 512, 0, 0, 0);
    bgemm_kernel<1, 0, false, false><<<dim3(64, 8, 1), 256, 0, stream>>>(
        xb, sa_wvb, sa_bv, nullptr, v, 4096, 512, 512, 0, 0, 0);

    // 4. self attention (S=1024): split-KV flash + combine -> attb bf16
    attn_part_kernel<32><<<dim3(4, 64, 4), 256, 0, stream>>>(
        q, k, v, selfPacc, selfPml, 1024, 1024, 256, NQ);
    attn_combine_kernel<4><<<NQ / 256, 256, 0, stream>>>(
        selfPacc, selfPml, attb, 1024, NQ);

    // 5. out proj + resid x -> h fp32
    bgemm_kernel<1, 0, true, false><<<dim3(64, 8, 1), 256, 0, stream>>>(
        attb, sa_wob, sa_bo, x, h, 4096, 512, 512, 0, 0, 0);

    // 6. LN1 -> hn fp32 + hnb bf16
    ln_kernel<false, true><<<4096, 256, 0, stream>>>(h, n1_g, n1_b, hn, hnb);

    // 7. cross-attn projections
    bgemm_kernel<1, 0, false, false><<<dim3(64, 8, 1), 256, 0, stream>>>(
        hnb, ca_wqb, ca_bq, nullptr, q, 4096, 512, 512, 0, 0, 0);
    bgemm_kernel<1, 0, false, false><<<dim3(32, 8, 1), 256, 0, stream>>>(
        crossb, ca_wkb, ca_bk, nullptr, k2, 2048, 512, 512, 0, 0, 0);
    bgemm_kernel<1, 0, false, false><<<dim3(32, 8, 1), 256, 0, stream>>>(
        crossb, ca_wvb, ca_bv, nullptr, v2, 2048, 512, 512, 0, 0, 0);

    // 8. cross attention (S=512): split-KV flash + combine -> attb bf16
    attn_part_kernel<32><<<dim3(4, 64, 4), 256, 0, stream>>>(
        q, k2, v2, crossPacc, crossPml, 1024, 512, 128, NQ);
    attn_combine_kernel<4><<<NQ / 256, 256, 0, stream>>>(
        crossPacc, crossPml, attb, 1024, NQ);

    // 9. out proj + resid hn -> h fp32
    bgemm_kernel<1, 0, true, false><<<dim3(64, 8, 1), 256, 0, stream>>>(
        attb, ca_wob, ca_bo, hn, h, 4096, 512, 512, 0, 0, 0);

    // 10. LN2 -> hn fp32 + hnb bf16
    ln_kernel<false, true><<<4096, 256, 0, stream>>>(h, n2_g, n2_b, hn, hnb);

    // 11. FFN up + exact gelu -> midb bf16  [4096,2048]
    bgemm_kernel<1, 2, false, true><<<dim3(64, 32, 1), 256, 0, stream>>>(
        hnb, ffn1b, ffn_b1, nullptr, midb, 4096, 2048, 512, 0, 0, 0);

    // 12. FFN down + resid hn -> h fp32  [4096,512] K=2048
    bgemm_kernel<1, 0, true, false><<<dim3(64, 8, 1), 256, 0, stream>>>(
        midb, ffn2b, ffn_b2, hn, h, 4096, 512, 2048, 0, 0, 0);

    // 13. LN3 + transpose -> d_out [B,512,L] fp32
    ln_kernel<true, false><<<4096, 256, 0, stream>>>(h, n3_g, n3_b, (float*)d_out, nullptr);
}

// Round 4
// 266.715 us; speedup vs baseline: 5.5844x; 1.8914x over previous
//
#include <hip/hip_runtime.h>
#include <hip/hip_bf16.h>
#include <math.h>

#define SCALE_ATTN 0.17677669529663687f  // 1/sqrt(32)

typedef unsigned short u16;
typedef __attribute__((ext_vector_type(8))) short bshort8;
typedef __attribute__((ext_vector_type(4))) short sshort4;
typedef __attribute__((ext_vector_type(4))) float f32x4;

__device__ inline u16 f2b(float f) {  // fp32 -> bf16 RNE
    union { float f; uint32_t u; } c;
    c.f = f;
    uint32_t u = c.u;
    return (u16)((u + 0x7fffu + ((u >> 16) & 1u)) >> 16);
}

__device__ inline void gload_lds16(const void* g, void* lds) {
    __builtin_amdgcn_global_load_lds(
        (const __attribute__((address_space(1))) void*)g,
        (__attribute__((address_space(3))) void*)lds, 16, 0, 0);
}

// ---------------- batched fp32->bf16 convert (11 weights + x) ----------------
struct WSrc { const float* p[12]; };
__global__ __launch_bounds__(256) void wconv_kernel(WSrc s, u16* __restrict__ dst) {
    long e = ((long)blockIdx.x * 256 + threadIdx.x) * 4;
    if (e >= 6553600) return;
    int w; long base;
    if (e < 2359296)      { w = (int)(e >> 18); base = (long)w << 18; }
    else if (e < 3407872) { w = 9;  base = 2359296; }
    else if (e < 4456448) { w = 10; base = 3407872; }
    else                  { w = 11; base = 4456448; }
    float4 v = *(const float4*)(s.p[w] + (e - base));
    dst[e + 0] = f2b(v.x); dst[e + 1] = f2b(v.y);
    dst[e + 2] = f2b(v.z); dst[e + 3] = f2b(v.w);
}

// ---------------- window |max-min| + eps -> transposed bf16 [b][n][c] ----------------
__global__ __launch_bounds__(256) void win_kernel(const float* __restrict__ G,
                                                  u16* __restrict__ Rt, int total) {
    int i = blockIdx.x * 256 + threadIdx.x;
    if (i >= total) return;
    const float4* p = reinterpret_cast<const float4*>(G) + (size_t)i * 2;
    float4 a = p[0], b = p[1];
    float mx = fmaxf(fmaxf(fmaxf(a.x, a.y), fmaxf(a.z, a.w)),
                     fmaxf(fmaxf(b.x, b.y), fmaxf(b.z, b.w)));
    float mn = fminf(fminf(fminf(a.x, a.y), fminf(a.z, a.w)),
                     fminf(fminf(b.x, b.y), fminf(b.z, b.w)));
    int b_ = i >> 18, c = (i >> 9) & 511, n = i & 511;
    Rt[((long)(b_ * 512 + n) << 9) + c] = f2b(fabsf(mx - mn) + 1e-6f);
}

// ---------------- bf16 MFMA GEMM ----------------
// C[m,n] = act(sum_k A[m,k]*Bt[n,k] + bias) (+resid). 64x64 tile, BK=64, 4 waves.
// BIASMODE: 0 none, 1 per-n, 2 per-m. ACT: 0 none, 1 relu, 2 gelu, 3 *SCALE_ATTN.
// OUTMODE: 0 fp32, 1 bf16, 2 bf16 batch-transposed (lbits = log2 rows/batch).
template <int BIASMODE, int ACT, bool RESID, int OUTMODE>
__global__ __launch_bounds__(256) void bgemm_kernel(
    const u16* __restrict__ A, const u16* __restrict__ Bt,
    const float* __restrict__ bias, const float* __restrict__ Rres,
    void* __restrict__ Cout, int M, int N, int K,
    long sA, long sB, long sC, int lbits) {
    A  += (long)blockIdx.z * sA;
    Bt += (long)blockIdx.z * sB;
    __shared__ u16 As[64 * 64];
    __shared__ u16 Bs[64 * 64];
    int tid = threadIdx.x;
    int lane = tid & 63, wv = tid >> 6;
    int wr = wv >> 1, wc = wv & 1;
    int m0 = blockIdx.x * 64, n0 = blockIdx.y * 64;
    f32x4 acc[2][2] = {};
    int srow = lane >> 3;
    int sbo = ((lane & 7) << 4) ^ (srow << 4);
    int selem = sbo >> 1;
    for (int k0 = 0; k0 < K; k0 += 64) {
        #pragma unroll
        for (int i = 0; i < 2; i++) {
            int r = i * 32 + wv * 8 + srow;
            gload_lds16(A + (long)(m0 + r) * K + k0 + selem,
                        (char*)As + (i * 32 + wv * 8) * 128);
            gload_lds16(Bt + (long)(n0 + r) * K + k0 + selem,
                        (char*)Bs + (i * 32 + wv * 8) * 128);
        }
        __syncthreads();
        #pragma unroll
        for (int ks = 0; ks < 2; ks++) {
            bshort8 af[2], bf[2];
            int kbo = ks * 64 + ((lane >> 4) << 4);
            #pragma unroll
            for (int f = 0; f < 2; f++) {
                int arow = wr * 32 + f * 16 + (lane & 15);
                af[f] = *(const bshort8*)((const char*)As + arow * 128 +
                                          (kbo ^ ((arow & 7) << 4)));
                int brow = wc * 32 + f * 16 + (lane & 15);
                bf[f] = *(const bshort8*)((const char*)Bs + brow * 128 +
                                          (kbo ^ ((brow & 7) << 4)));
            }
            #pragma unroll
            for (int fi = 0; fi < 2; fi++)
                #pragma unroll
                for (int fj = 0; fj < 2; fj++)
                    acc[fi][fj] = __builtin_amdgcn_mfma_f32_16x16x32_bf16(
                        af[fi], bf[fj], acc[fi][fj], 0, 0, 0);
        }
        __syncthreads();
    }
    #pragma unroll
    for (int fi = 0; fi < 2; fi++)
        #pragma unroll
        for (int fj = 0; fj < 2; fj++)
            #pragma unroll
            for (int r = 0; r < 4; r++) {
                int row = m0 + wr * 32 + fi * 16 + ((lane >> 4) << 2) + r;
                int col = n0 + wc * 32 + fj * 16 + (lane & 15);
                float v = acc[fi][fj][r];
                if (BIASMODE == 1) v += bias[col];
                if (BIASMODE == 2) v += bias[row];
                if (ACT == 1) v = fmaxf(v, 0.f);
                if (ACT == 2) v = 0.5f * v * (1.f + erff(v * 0.70710678118654752f));
                if (ACT == 3) v *= SCALE_ATTN;
                if (RESID) v += Rres[(long)row * N + col];
                if (OUTMODE == 2) {
                    int rl = row & ((1 << lbits) - 1);
                    long off = ((long)(row >> lbits) * N + col) << lbits;
                    ((u16*)Cout)[off + rl] = f2b(v);
                } else {
                    long off = (long)blockIdx.z * sC + (long)row * N + col;
                    if (OUTMODE == 1) ((u16*)Cout)[off] = f2b(v);
                    else              ((float*)Cout)[off] = v;
                }
            }
}

// ---------------- fused MFMA flash attention ----------------
// Q [B,L,512] bf16 (pre-scaled), K [B,S,512] bf16, Vt [B,512,S] bf16,
// O [B,L,512] bf16. Grid (L/64, B*16), 4 waves; wave owns 16 queries.
__global__ __launch_bounds__(256) void attn_mfma_kernel(
    const u16* __restrict__ Q, const u16* __restrict__ K,
    const u16* __restrict__ Vt, u16* __restrict__ O, int L, int S) {
    int bh = blockIdx.y;
    int b = bh >> 4, h = bh & 15;
    int tid = threadIdx.x;
    int lane = tid & 63, wv = tid >> 6;
    int q0 = blockIdx.x * 64 + wv * 16;
    int qr = lane & 15, g = lane >> 4;
    __shared__ __align__(16) u16 Plds[4][16][40];  // row stride 80B (16B-aligned, 2-way banks)

    bshort8 qf = *(const bshort8*)(Q + ((long)(b * L + q0 + qr)) * 512 + h * 32 + g * 8);
    const u16* Kb = K + (long)b * S * 512 + h * 32;
    const u16* Vb = Vt + ((long)b * 512 + h * 32) * S;

    f32x4 acc0 = {}, acc1 = {};
    float m = -1e30f, lsum = 0.f;

    for (int s0 = 0; s0 < S; s0 += 32) {
        // K fragments: A[row=key, k=d]
        bshort8 kf0 = *(const bshort8*)(Kb + (long)(s0 + qr) * 512 + g * 8);
        bshort8 kf1 = *(const bshort8*)(Kb + (long)(s0 + 16 + qr) * 512 + g * 8);
        // S^T tiles: D[key, query], col=lane&15=query, row=g*4+r=key
        f32x4 st0 = __builtin_amdgcn_mfma_f32_16x16x32_bf16(kf0, qf, (f32x4){0.f,0.f,0.f,0.f}, 0, 0, 0);
        f32x4 st1 = __builtin_amdgcn_mfma_f32_16x16x32_bf16(kf1, qf, (f32x4){0.f,0.f,0.f,0.f}, 0, 0, 0);
        // online softmax for this 32-key chunk
        float cm = fmaxf(fmaxf(fmaxf(st0[0], st0[1]), fmaxf(st0[2], st0[3])),
                         fmaxf(fmaxf(st1[0], st1[1]), fmaxf(st1[2], st1[3])));
        cm = fmaxf(cm, __shfl_xor(cm, 16));
        cm = fmaxf(cm, __shfl_xor(cm, 32));
        float mnew = fmaxf(m, cm);
        float corr = __expf(m - mnew);
        m = mnew;
        float ps = 0.f;
        u16 pb[8];
        #pragma unroll
        for (int r = 0; r < 4; r++) { float p = __expf(st0[r] - m); ps += p; pb[r] = f2b(p); }
        #pragma unroll
        for (int r = 0; r < 4; r++) { float p = __expf(st1[r] - m); ps += p; pb[4 + r] = f2b(p); }
        lsum = lsum * corr + ps;
        // reshape P: score layout -> B-fragment layout via per-wave LDS bounce
        sshort4 w0 = { (short)pb[0], (short)pb[1], (short)pb[2], (short)pb[3] };
        sshort4 w1 = { (short)pb[4], (short)pb[5], (short)pb[6], (short)pb[7] };
        *(sshort4*)(&Plds[wv][qr][g * 4]) = w0;
        *(sshort4*)(&Plds[wv][qr][16 + g * 4]) = w1;
        asm volatile("s_waitcnt lgkmcnt(0)" ::: "memory");
        __builtin_amdgcn_sched_barrier(0);
        bshort8 pf = *(const bshort8*)(&Plds[wv][qr][g * 8]);
        // V^T fragments: A[row=d, k=key]
        bshort8 vf0 = *(const bshort8*)(Vb + (long)qr * S + s0 + g * 8);
        bshort8 vf1 = *(const bshort8*)(Vb + (long)(16 + qr) * S + s0 + g * 8);
        // rescale then accumulate O^T: D[d, query], col=query
        #pragma unroll
        for (int r = 0; r < 4; r++) { acc0[r] *= corr; acc1[r] *= corr; }
        acc0 = __builtin_amdgcn_mfma_f32_16x16x32_bf16(vf0, pf, acc0, 0, 0, 0);
        acc1 = __builtin_amdgcn_mfma_f32_16x16x32_bf16(vf1, pf, acc1, 0, 0, 0);
    }
    lsum += __shfl_xor(lsum, 16);
    lsum += __shfl_xor(lsum, 32);
    float inv = 1.f / lsum;
    u16* op = O + ((long)(b * L + q0 + qr)) * 512 + h * 32 + g * 4;
    sshort4 o0, o1;
    #pragma unroll
    for (int r = 0; r < 4; r++) {
        o0[r] = (short)f2b(acc0[r] * inv);
        o1[r] = (short)f2b(acc1[r] * inv);
    }
    *(sshort4*)op = o0;
    *(sshort4*)(op + 16) = o1;
}

// ---------------- layernorm over 512; optional bf16 dual-store / transposed out ------
template <bool TRANS, bool DUAL>
__global__ __launch_bounds__(256) void ln_kernel(const float* __restrict__ X,
                                                 const float* __restrict__ g,
                                                 const float* __restrict__ bt,
                                                 float* __restrict__ Y,
                                                 u16* __restrict__ Yb) {
    int row = blockIdx.x;
    const float* xr = X + (long)row * 512;
    int t = threadIdx.x;
    float x0 = xr[t], x1 = xr[t + 256];
    float s = x0 + x1, ss = x0 * x0 + x1 * x1;
    #pragma unroll
    for (int off = 32; off > 0; off >>= 1) {
        s += __shfl_down(s, off);
        ss += __shfl_down(ss, off);
    }
    __shared__ float sred[4], ssred[4];
    int wid = t >> 6;
    if ((t & 63) == 0) { sred[wid] = s; ssred[wid] = ss; }
    __syncthreads();
    float ts = sred[0] + sred[1] + sred[2] + sred[3];
    float tss = ssred[0] + ssred[1] + ssred[2] + ssred[3];
    float mean = ts * (1.f / 512.f);
    float var = tss * (1.f / 512.f) - mean * mean;
    float rstd = rsqrtf(var + 1e-5f);
    float y0 = (x0 - mean) * rstd * g[t] + bt[t];
    float y1 = (x1 - mean) * rstd * g[t + 256] + bt[t + 256];
    if (TRANS) {
        int b = row >> 10, l = row & 1023;
        Y[((long)b * 512 + t) * 1024 + l] = y0;
        Y[((long)b * 512 + t + 256) * 1024 + l] = y1;
    } else {
        Y[(long)row * 512 + t] = y0;
        Y[(long)row * 512 + t + 256] = y1;
    }
    if (DUAL) {
        Yb[(long)row * 512 + t] = f2b(y0);
        Yb[(long)row * 512 + t + 256] = f2b(y1);
    }
}

extern "C" void kernel_launch(void* const* d_in, const int* in_sizes, int n_in,
                              void* d_out, int out_size, void* d_ws, size_t ws_size,
                              hipStream_t stream) {
    const float* x      = (const float*)d_in[0];
    const float* gfeat  = (const float*)d_in[1];
    const float* conv_w = (const float*)d_in[2];
    const float* conv_b = (const float*)d_in[3];
    const float* sa_wq = (const float*)d_in[4];
    const float* sa_bq = (const float*)d_in[5];
    const float* sa_wk = (const float*)d_in[6];
    const float* sa_bk = (const float*)d_in[7];
    const float* sa_wv = (const float*)d_in[8];
    const float* sa_bv = (const float*)d_in[9];
    const float* sa_wo = (const float*)d_in[10];
    const float* sa_bo = (const float*)d_in[11];
    const float* ca_wq = (const float*)d_in[12];
    const float* ca_bq = (const float*)d_in[13];
    const float* ca_wk = (const float*)d_in[14];
    const float* ca_bk = (const float*)d_in[15];
    const float* ca_wv = (const float*)d_in[16];
    const float* ca_bv = (const float*)d_in[17];
    const float* ca_wo = (const float*)d_in[18];
    const float* ca_bo = (const float*)d_in[19];
    const float* ffn_w1 = (const float*)d_in[20];
    const float* ffn_b1 = (const float*)d_in[21];
    const float* ffn_w2 = (const float*)d_in[22];
    const float* ffn_b2 = (const float*)d_in[23];
    const float* n1_g = (const float*)d_in[24];
    const float* n1_b = (const float*)d_in[25];
    const float* n2_g = (const float*)d_in[26];
    const float* n2_b = (const float*)d_in[27];
    const float* n3_g = (const float*)d_in[28];
    const float* n3_b = (const float*)d_in[29];
    (void)ws_size; (void)n_in; (void)in_sizes; (void)out_size;

    const long M_ = 1048576;
    float* W0 = (float*)d_ws;
    float* h   = W0;                 // [0, 2M) fp32
    float* hn  = W0 + 2 * M_;        // [2M, 4M) fp32
    u16* U = (u16*)(W0 + 4 * M_);
    u16* qb     = U;                 // 2M u16
    u16* kb     = U + 2 * M_;        // 2M
    u16* vtb    = U + 4 * M_;        // 2M   [4][512][1024]
    u16* k2b    = U + 6 * M_;        // 1M
    u16* v2tb   = U + 7 * M_;        // 1M   [4][512][512]
    u16* attb   = U + 8 * M_;        // 2M
    u16* hnb    = U + 10 * M_;       // 2M
    u16* midb   = U + 12 * M_;       // 8M
    u16* wsb    = U + 20 * M_;       // 6.55M
    u16* res_tb = U + 27 * M_;       // 1M
    u16* crossb = U + 28 * M_;       // 1M

    const u16* conv_wb = wsb;
    const u16* sa_wqb = wsb + 262144, *sa_wkb = wsb + 524288;
    const u16* sa_wvb = wsb + 786432, *sa_wob = wsb + 1048576;
    const u16* ca_wqb = wsb + 1310720, *ca_wkb = wsb + 1572864;
    const u16* ca_wvb = wsb + 1835008, *ca_wob = wsb + 2097152;
    const u16* ffn1b = wsb + 2359296, *ffn2b = wsb + 3407872;
    const u16* xb = wsb + 4456448;

    // 0. convert weights + x to bf16
    WSrc ws;
    ws.p[0] = conv_w; ws.p[1] = sa_wq; ws.p[2] = sa_wk; ws.p[3] = sa_wv;
    ws.p[4] = sa_wo; ws.p[5] = ca_wq; ws.p[6] = ca_wk; ws.p[7] = ca_wv;
    ws.p[8] = ca_wo; ws.p[9] = ffn_w1; ws.p[10] = ffn_w2; ws.p[11] = x;
    wconv_kernel<<<6400, 256, 0, stream>>>(ws, wsb);

    // 1. window |max-min|+eps, transposed bf16: res_tb [b][n][c]
    win_kernel<<<4096, 256, 0, stream>>>(gfeat, res_tb, 4 * 512 * 512);

    // 2. conv+relu: crossb[b][o][n]
    bgemm_kernel<2, 1, false, 1><<<dim3(8, 8, 4), 256, 0, stream>>>(
        conv_wb, res_tb, conv_b, nullptr, crossb, 512, 512, 512, 0, 262144, 262144, 0);

    // 3. self-attn projections: Q (pre-scaled) bf16, K bf16, V^T bf16
    bgemm_kernel<1, 3, false, 1><<<dim3(64, 8, 1), 256, 0, stream>>>(
        xb, sa_wqb, sa_bq, nullptr, qb, 4096, 512, 512, 0, 0, 0, 0);
    bgemm_kernel<1, 0, false, 1><<<dim3(64, 8, 1), 256, 0, stream>>>(
        xb, sa_wkb, sa_bk, nullptr, kb, 4096, 512, 512, 0, 0, 0, 0);
    bgemm_kernel<1, 0, false, 2><<<dim3(64, 8, 1), 256, 0, stream>>>(
        xb, sa_wvb, sa_bv, nullptr, vtb, 4096, 512, 512, 0, 0, 0, 10);

    // 4. self attention (S=1024) -> attb bf16
    attn_mfma_kernel<<<dim3(16, 64), 256, 0, stream>>>(qb, kb, vtb, attb, 1024, 1024);

    // 5. out proj + resid x -> h fp32
    bgemm_kernel<1, 0, true, 0><<<dim3(64, 8, 1), 256, 0, stream>>>(
        attb, sa_wob, sa_bo, x, h, 4096, 512, 512, 0, 0, 0, 0);

    // 6. LN1 -> hn fp32 + hnb bf16
    ln_kernel<false, true><<<4096, 256, 0, stream>>>(h, n1_g, n1_b, hn, hnb);

    // 7. cross-attn projections
    bgemm_kernel<1, 3, false, 1><<<dim3(64, 8, 1), 256, 0, stream>>>(
        hnb, ca_wqb, ca_bq, nullptr, qb, 4096, 512, 512, 0, 0, 0, 0);
    bgemm_kernel<1, 0, false, 1><<<dim3(32, 8, 1), 256, 0, stream>>>(
        crossb, ca_wkb, ca_bk, nullptr, k2b, 2048, 512, 512, 0, 0, 0, 0);
    bgemm_kernel<1, 0, false, 2><<<dim3(32, 8, 1), 256, 0, stream>>>(
        crossb, ca_wvb, ca_bv, nullptr, v2tb, 2048, 512, 512, 0, 0, 0, 9);

    // 8. cross attention (S=512) -> attb bf16
    attn_mfma_kernel<<<dim3(16, 64), 256, 0, stream>>>(qb, k2b, v2tb, attb, 1024, 512);

    // 9. out proj + resid hn -> h fp32
    bgemm_kernel<1, 0, true, 0><<<dim3(64, 8, 1), 256, 0, stream>>>(
        attb, ca_wob, ca_bo, hn, h, 4096, 512, 512, 0, 0, 0, 0);

    // 10. LN2 -> hn fp32 + hnb bf16
    ln_kernel<false, true><<<4096, 256, 0, stream>>>(h, n2_g, n2_b, hn, hnb);

    // 11. FFN up + exact gelu -> midb bf16  [4096,2048]
    bgemm_kernel<1, 2, false, 1><<<dim3(64, 32, 1), 256, 0, stream>>>(
        hnb, ffn1b, ffn_b1, nullptr, midb, 4096, 2048, 512, 0, 0, 0, 0);

    // 12. FFN down + resid hn -> h fp32  [4096,512] K=2048
    bgemm_kernel<1, 0, true, 0><<<dim3(64, 8, 1), 256, 0, stream>>>(
        midb, ffn2b, ffn_b2, hn, h, 4096, 512, 2048, 0, 0, 0, 0);

    // 13. LN3 + transpose -> d_out [B,512,L] fp32
    ln_kernel<true, false><<<4096, 256, 0, stream>>>(h, n3_g, n3_b, (float*)d_out, nullptr);
}

// Round 5
// 249.745 us; speedup vs baseline: 5.9639x; 1.0679x over previous
//
#include <hip/hip_runtime.h>
#include <hip/hip_bf16.h>
#include <math.h>

#define SCALE_ATTN 0.17677669529663687f  // 1/sqrt(32)

typedef unsigned short u16;
typedef unsigned int u32;
typedef __attribute__((ext_vector_type(8))) short bshort8;
typedef __attribute__((ext_vector_type(4))) short sshort4;
typedef __attribute__((ext_vector_type(4))) float f32x4;
typedef __attribute__((ext_vector_type(4))) u32 u32x4;

__device__ inline u16 f2b(float f) {  // fp32 -> bf16 RNE
    union { float f; uint32_t u; } c;
    c.f = f;
    uint32_t u = c.u;
    return (u16)((u + 0x7fffu + ((u >> 16) & 1u)) >> 16);
}

__device__ __forceinline__ u32 cvtpk(float a, float b) {  // {lo=bf16(a), hi=bf16(b)}
    u32 r;
    asm("v_cvt_pk_bf16_f32 %0, %1, %2" : "=v"(r) : "v"(a), "v"(b));
    return r;
}

__device__ inline void gload_lds16(const void* g, void* lds) {
    __builtin_amdgcn_global_load_lds(
        (const __attribute__((address_space(1))) void*)g,
        (__attribute__((address_space(3))) void*)lds, 16, 0, 0);
}

// ---------------- batched fp32->bf16 convert (11 weights + x) ----------------
struct WSrc { const float* p[12]; };
__global__ __launch_bounds__(256) void wconv_kernel(WSrc s, u16* __restrict__ dst) {
    long e = ((long)blockIdx.x * 256 + threadIdx.x) * 4;
    if (e >= 6553600) return;
    int w; long base;
    if (e < 2359296)      { w = (int)(e >> 18); base = (long)w << 18; }
    else if (e < 3407872) { w = 9;  base = 2359296; }
    else if (e < 4456448) { w = 10; base = 3407872; }
    else                  { w = 11; base = 4456448; }
    float4 v = *(const float4*)(s.p[w] + (e - base));
    dst[e + 0] = f2b(v.x); dst[e + 1] = f2b(v.y);
    dst[e + 2] = f2b(v.z); dst[e + 3] = f2b(v.w);
}

// ---------------- window |max-min| + eps -> transposed bf16 [b][n][c] ----------------
__global__ __launch_bounds__(256) void win_kernel(const float* __restrict__ G,
                                                  u16* __restrict__ Rt, int total) {
    int i = blockIdx.x * 256 + threadIdx.x;
    if (i >= total) return;
    const float4* p = reinterpret_cast<const float4*>(G) + (size_t)i * 2;
    float4 a = p[0], b = p[1];
    float mx = fmaxf(fmaxf(fmaxf(a.x, a.y), fmaxf(a.z, a.w)),
                     fmaxf(fmaxf(b.x, b.y), fmaxf(b.z, b.w)));
    float mn = fminf(fminf(fminf(a.x, a.y), fminf(a.z, a.w)),
                     fminf(fminf(b.x, b.y), fminf(b.z, b.w)));
    int b_ = i >> 18, c = (i >> 9) & 511, n = i & 511;
    Rt[((long)(b_ * 512 + n) << 9) + c] = f2b(fabsf(mx - mn) + 1e-6f);
}

// ---------------- bf16 MFMA GEMM ----------------
// C[m,n] = act(sum_k A[m,k]*Bt[n,k] + bias) (+resid). 64x64 tile, BK=64, 4 waves.
// BIASMODE: 0 none, 1 per-n, 2 per-m. ACT: 0 none, 1 relu, 2 gelu, 3 *SCALE_ATTN.
// OUTMODE: 0 fp32, 1 bf16, 2 bf16 batch-transposed (lbits),
//          3 fused QKV split (Cout=q *SCALE, D1=k, D2=v transposed lbits=10),
//          4 fused KV split (Cout=k2, D2=v2 transposed lbits=9).
template <int BIASMODE, int ACT, bool RESID, int OUTMODE>
__global__ __launch_bounds__(256) void bgemm_kernel(
    const u16* __restrict__ A, const u16* __restrict__ Bt,
    const float* __restrict__ bias, const float* __restrict__ Rres,
    void* __restrict__ Cout, int M, int N, int K,
    long sA, long sB, long sC,
    u16* __restrict__ D1, u16* __restrict__ D2,
    const float* __restrict__ bias1, const float* __restrict__ bias2, int lbits) {
    A  += (long)blockIdx.z * sA;
    Bt += (long)blockIdx.z * sB;
    __shared__ u16 As[64 * 64];
    __shared__ u16 Bs[64 * 64];
    int tid = threadIdx.x;
    int lane = tid & 63, wv = tid >> 6;
    int wr = wv >> 1, wc = wv & 1;
    int m0 = blockIdx.x * 64, n0 = blockIdx.y * 64;
    f32x4 acc[2][2] = {};
    int srow = lane >> 3;
    int sbo = ((lane & 7) << 4) ^ (srow << 4);
    int selem = sbo >> 1;
    for (int k0 = 0; k0 < K; k0 += 64) {
        #pragma unroll
        for (int i = 0; i < 2; i++) {
            int r = i * 32 + wv * 8 + srow;
            gload_lds16(A + (long)(m0 + r) * K + k0 + selem,
                        (char*)As + (i * 32 + wv * 8) * 128);
            gload_lds16(Bt + (long)(n0 + r) * K + k0 + selem,
                        (char*)Bs + (i * 32 + wv * 8) * 128);
        }
        __syncthreads();
        #pragma unroll
        for (int ks = 0; ks < 2; ks++) {
            bshort8 af[2], bf[2];
            int kbo = ks * 64 + ((lane >> 4) << 4);
            #pragma unroll
            for (int f = 0; f < 2; f++) {
                int arow = wr * 32 + f * 16 + (lane & 15);
                af[f] = *(const bshort8*)((const char*)As + arow * 128 +
                                          (kbo ^ ((arow & 7) << 4)));
                int brow = wc * 32 + f * 16 + (lane & 15);
                bf[f] = *(const bshort8*)((const char*)Bs + brow * 128 +
                                          (kbo ^ ((brow & 7) << 4)));
            }
            #pragma unroll
            for (int fi = 0; fi < 2; fi++)
                #pragma unroll
                for (int fj = 0; fj < 2; fj++)
                    acc[fi][fj] = __builtin_amdgcn_mfma_f32_16x16x32_bf16(
                        af[fi], bf[fj], acc[fi][fj], 0, 0, 0);
        }
        __syncthreads();
    }
    #pragma unroll
    for (int fi = 0; fi < 2; fi++)
        #pragma unroll
        for (int fj = 0; fj < 2; fj++)
            #pragma unroll
            for (int r = 0; r < 4; r++) {
                int row = m0 + wr * 32 + fi * 16 + ((lane >> 4) << 2) + r;
                int col = n0 + wc * 32 + fj * 16 + (lane & 15);
                float v = acc[fi][fj][r];
                if (OUTMODE == 3) {
                    int grp = col >> 9, c = col & 511;
                    float bb = (grp == 0) ? bias[c] : (grp == 1) ? bias1[c] : bias2[c];
                    float vv = v + bb;
                    if (grp == 0)
                        ((u16*)Cout)[(long)row * 512 + c] = f2b(vv * SCALE_ATTN);
                    else if (grp == 1)
                        D1[(long)row * 512 + c] = f2b(vv);
                    else
                        D2[((long)((row >> 10) * 512 + c) << 10) + (row & 1023)] = f2b(vv);
                } else if (OUTMODE == 4) {
                    int grp = col >> 9, c = col & 511;
                    float vv = v + ((grp == 0) ? bias[c] : bias1[c]);
                    if (grp == 0)
                        ((u16*)Cout)[(long)row * 512 + c] = f2b(vv);
                    else
                        D2[((long)((row >> 9) * 512 + c) << 9) + (row & 511)] = f2b(vv);
                } else {
                    if (BIASMODE == 1) v += bias[col];
                    if (BIASMODE == 2) v += bias[row];
                    if (ACT == 1) v = fmaxf(v, 0.f);
                    if (ACT == 2) v = 0.5f * v * (1.f + erff(v * 0.70710678118654752f));
                    if (ACT == 3) v *= SCALE_ATTN;
                    if (RESID) v += Rres[(long)row * N + col];
                    if (OUTMODE == 2) {
                        int rl = row & ((1 << lbits) - 1);
                        long off = ((long)(row >> lbits) * N + col) << lbits;
                        ((u16*)Cout)[off + rl] = f2b(v);
                    } else {
                        long off = (long)blockIdx.z * sC + (long)row * N + col;
                        if (OUTMODE == 1) ((u16*)Cout)[off] = f2b(v);
                        else              ((float*)Cout)[off] = v;
                    }
                }
            }
}

// ---------------- fused MFMA flash attention, zero-shuffle P ----------------
// Q [B,L,512] bf16 (pre-scaled), K [B,S,512] bf16, Vt [B,512,S] bf16, O bf16.
// Grid (bh=64, L/64), 4 waves, wave owns 16 queries, KVBLK=64, K-prefetch.
// Score MFMA loads K rows PERMUTED (lane qr -> key 8*(qr>>2)+(qr&3)) so the
// score output IS the PV B-fragment layout: lane (qr,g) holds keys 8g+0..7.
struct KFr { bshort8 a0, a1, a2, a3; };
struct VFr { bshort8 v00, v01, v10, v11; };

__global__ __launch_bounds__(256) void attn_mfma_kernel(
    const u16* __restrict__ Q, const u16* __restrict__ K,
    const u16* __restrict__ Vt, u16* __restrict__ O, int L, int S) {
    int bh = blockIdx.x;
    int b = bh >> 4, h = bh & 15;
    int tid = threadIdx.x;
    int lane = tid & 63, wv = tid >> 6;
    int q0 = blockIdx.y * 64 + wv * 16;
    int qr = lane & 15, g = lane >> 4;
    int g8 = g * 8;
    int kperm = 8 * (qr >> 2) + (qr & 3);

    bshort8 qf = *(const bshort8*)(Q + ((long)(b * L + q0 + qr)) * 512 + h * 32 + g8);
    const u16* Kb = K + (long)b * S * 512 + h * 32;
    const u16* Vb = Vt + ((long)b * 512 + h * 32) * S;

    f32x4 acc0 = {}, acc1 = {};
    float m = -1e30f, lsum = 0.f;

    auto loadK = [&](int s0) {
        KFr r;
        r.a0 = *(const bshort8*)(Kb + (long)(s0 + kperm) * 512 + g8);
        r.a1 = *(const bshort8*)(Kb + (long)(s0 + kperm + 4) * 512 + g8);
        r.a2 = *(const bshort8*)(Kb + (long)(s0 + 32 + kperm) * 512 + g8);
        r.a3 = *(const bshort8*)(Kb + (long)(s0 + 32 + kperm + 4) * 512 + g8);
        return r;
    };
    auto loadV = [&](int s0) {
        VFr r;
        r.v00 = *(const bshort8*)(Vb + (long)qr * S + s0 + g8);
        r.v01 = *(const bshort8*)(Vb + (long)qr * S + s0 + 32 + g8);
        r.v10 = *(const bshort8*)(Vb + (long)(16 + qr) * S + s0 + g8);
        r.v11 = *(const bshort8*)(Vb + (long)(16 + qr) * S + s0 + 32 + g8);
        return r;
    };

    auto process = [&](const KFr& kf, const VFr& vf) {
        f32x4 z = {0.f, 0.f, 0.f, 0.f};
        f32x4 st0 = __builtin_amdgcn_mfma_f32_16x16x32_bf16(kf.a0, qf, z, 0, 0, 0);
        f32x4 st1 = __builtin_amdgcn_mfma_f32_16x16x32_bf16(kf.a1, qf, z, 0, 0, 0);
        f32x4 st2 = __builtin_amdgcn_mfma_f32_16x16x32_bf16(kf.a2, qf, z, 0, 0, 0);
        f32x4 st3 = __builtin_amdgcn_mfma_f32_16x16x32_bf16(kf.a3, qf, z, 0, 0, 0);
        float c0 = fmaxf(fmaxf(st0[0], st0[1]), fmaxf(st0[2], st0[3]));
        float c1 = fmaxf(fmaxf(st1[0], st1[1]), fmaxf(st1[2], st1[3]));
        float c2 = fmaxf(fmaxf(st2[0], st2[1]), fmaxf(st2[2], st2[3]));
        float c3 = fmaxf(fmaxf(st3[0], st3[1]), fmaxf(st3[2], st3[3]));
        float cm = fmaxf(fmaxf(c0, c1), fmaxf(c2, c3));
        cm = fmaxf(cm, __shfl_xor(cm, 16));
        cm = fmaxf(cm, __shfl_xor(cm, 32));
        float mnew = fmaxf(m, cm);
        float corr = __expf(m - mnew);
        m = mnew;
        float p0[4], p1[4], p2[4], p3[4];
        #pragma unroll
        for (int r = 0; r < 4; r++) {
            p0[r] = __expf(st0[r] - m);
            p1[r] = __expf(st1[r] - m);
            p2[r] = __expf(st2[r] - m);
            p3[r] = __expf(st3[r] - m);
        }
        float ps = ((p0[0] + p0[1]) + (p0[2] + p0[3])) + ((p1[0] + p1[1]) + (p1[2] + p1[3])) +
                   ((p2[0] + p2[1]) + (p2[2] + p2[3])) + ((p3[0] + p3[1]) + (p3[2] + p3[3]));
        lsum = fmaf(lsum, corr, ps);
        u32x4 P0 = { cvtpk(p0[0], p0[1]), cvtpk(p0[2], p0[3]),
                     cvtpk(p1[0], p1[1]), cvtpk(p1[2], p1[3]) };
        u32x4 P1 = { cvtpk(p2[0], p2[1]), cvtpk(p2[2], p2[3]),
                     cvtpk(p3[0], p3[1]), cvtpk(p3[2], p3[3]) };
        bshort8 pf0 = *(bshort8*)&P0;
        bshort8 pf1 = *(bshort8*)&P1;
        #pragma unroll
        for (int r = 0; r < 4; r++) { acc0[r] *= corr; acc1[r] *= corr; }
        acc0 = __builtin_amdgcn_mfma_f32_16x16x32_bf16(vf.v00, pf0, acc0, 0, 0, 0);
        acc0 = __builtin_amdgcn_mfma_f32_16x16x32_bf16(vf.v01, pf1, acc0, 0, 0, 0);
        acc1 = __builtin_amdgcn_mfma_f32_16x16x32_bf16(vf.v10, pf0, acc1, 0, 0, 0);
        acc1 = __builtin_amdgcn_mfma_f32_16x16x32_bf16(vf.v11, pf1, acc1, 0, 0, 0);
    };

    KFr ka = loadK(0);
    for (int s0 = 0; s0 < S; s0 += 128) {
        VFr va = loadV(s0);
        KFr kb_ = loadK(s0 + 64);
        process(ka, va);
        VFr vb = loadV(s0 + 64);
        if (s0 + 128 < S) ka = loadK(s0 + 128);
        process(kb_, vb);
    }

    lsum += __shfl_xor(lsum, 16);
    lsum += __shfl_xor(lsum, 32);
    float inv = 1.f / lsum;
    u16* op = O + ((long)(b * L + q0 + qr)) * 512 + h * 32 + g * 4;
    sshort4 o0, o1;
    #pragma unroll
    for (int r = 0; r < 4; r++) {
        o0[r] = (short)f2b(acc0[r] * inv);
        o1[r] = (short)f2b(acc1[r] * inv);
    }
    *(sshort4*)op = o0;
    *(sshort4*)(op + 16) = o1;
}

// ---------------- layernorm over 512; optional bf16 dual-store / transposed out ------
template <bool TRANS, bool DUAL>
__global__ __launch_bounds__(256) void ln_kernel(const float* __restrict__ X,
                                                 const float* __restrict__ g,
                                                 const float* __restrict__ bt,
                                                 float* __restrict__ Y,
                                                 u16* __restrict__ Yb) {
    int row = blockIdx.x;
    const float* xr = X + (long)row * 512;
    int t = threadIdx.x;
    float x0 = xr[t], x1 = xr[t + 256];
    float s = x0 + x1, ss = x0 * x0 + x1 * x1;
    #pragma unroll
    for (int off = 32; off > 0; off >>= 1) {
        s += __shfl_down(s, off);
        ss += __shfl_down(ss, off);
    }
    __shared__ float sred[4], ssred[4];
    int wid = t >> 6;
    if ((t & 63) == 0) { sred[wid] = s; ssred[wid] = ss; }
    __syncthreads();
    float ts = sred[0] + sred[1] + sred[2] + sred[3];
    float tss = ssred[0] + ssred[1] + ssred[2] + ssred[3];
    float mean = ts * (1.f / 512.f);
    float var = tss * (1.f / 512.f) - mean * mean;
    float rstd = rsqrtf(var + 1e-5f);
    float y0 = (x0 - mean) * rstd * g[t] + bt[t];
    float y1 = (x1 - mean) * rstd * g[t + 256] + bt[t + 256];
    if (TRANS) {
        int b = row >> 10, l = row & 1023;
        Y[((long)b * 512 + t) * 1024 + l] = y0;
        Y[((long)b * 512 + t + 256) * 1024 + l] = y1;
    } else {
        Y[(long)row * 512 + t] = y0;
        Y[(long)row * 512 + t + 256] = y1;
    }
    if (DUAL) {
        Yb[(long)row * 512 + t] = f2b(y0);
        Yb[(long)row * 512 + t + 256] = f2b(y1);
    }
}

extern "C" void kernel_launch(void* const* d_in, const int* in_sizes, int n_in,
                              void* d_out, int out_size, void* d_ws, size_t ws_size,
                              hipStream_t stream) {
    const float* x      = (const float*)d_in[0];
    const float* gfeat  = (const float*)d_in[1];
    const float* conv_w = (const float*)d_in[2];
    const float* conv_b = (const float*)d_in[3];
    const float* sa_wq = (const float*)d_in[4];
    const float* sa_bq = (const float*)d_in[5];
    const float* sa_wk = (const float*)d_in[6];
    const float* sa_bk = (const float*)d_in[7];
    const float* sa_wv = (const float*)d_in[8];
    const float* sa_bv = (const float*)d_in[9];
    const float* sa_wo = (const float*)d_in[10];
    const float* sa_bo = (const float*)d_in[11];
    const float* ca_wq = (const float*)d_in[12];
    const float* ca_bq = (const float*)d_in[13];
    const float* ca_wk = (const float*)d_in[14];
    const float* ca_bk = (const float*)d_in[15];
    const float* ca_wv = (const float*)d_in[16];
    const float* ca_bv = (const float*)d_in[17];
    const float* ca_wo = (const float*)d_in[18];
    const float* ca_bo = (const float*)d_in[19];
    const float* ffn_w1 = (const float*)d_in[20];
    const float* ffn_b1 = (const float*)d_in[21];
    const float* ffn_w2 = (const float*)d_in[22];
    const float* ffn_b2 = (const float*)d_in[23];
    const float* n1_g = (const float*)d_in[24];
    const float* n1_b = (const float*)d_in[25];
    const float* n2_g = (const float*)d_in[26];
    const float* n2_b = (const float*)d_in[27];
    const float* n3_g = (const float*)d_in[28];
    const float* n3_b = (const float*)d_in[29];
    (void)ws_size; (void)n_in; (void)in_sizes; (void)out_size;

    const long M_ = 1048576;
    float* W0 = (float*)d_ws;
    float* h   = W0;                 // [0, 2M) fp32
    float* hn  = W0 + 2 * M_;        // [2M, 4M) fp32
    u16* U = (u16*)(W0 + 4 * M_);
    u16* qb     = U;                 // 2M u16
    u16* kb     = U + 2 * M_;        // 2M
    u16* vtb    = U + 4 * M_;        // 2M   [4][512][1024]
    u16* k2b    = U + 6 * M_;        // 1M
    u16* v2tb   = U + 7 * M_;        // 1M   [4][512][512]
    u16* attb   = U + 8 * M_;        // 2M
    u16* hnb    = U + 10 * M_;       // 2M
    u16* midb   = U + 12 * M_;       // 8M
    u16* wsb    = U + 20 * M_;       // 6.55M
    u16* res_tb = U + 27 * M_;       // 1M
    u16* crossb = U + 28 * M_;       // 1M

    const u16* conv_wb = wsb;
    const u16* sa_wqb = wsb + 262144;   // wq,wk,wv contiguous -> fused QKV weight
    const u16* sa_wob = wsb + 1048576;
    const u16* ca_wqb = wsb + 1310720;
    const u16* ca_wkb = wsb + 1572864;  // wk,wv contiguous -> fused KV weight
    const u16* ca_wob = wsb + 2097152;
    const u16* ffn1b = wsb + 2359296, *ffn2b = wsb + 3407872;
    const u16* xb = wsb + 4456448;

    // 0. convert weights + x to bf16
    WSrc ws;
    ws.p[0] = conv_w; ws.p[1] = sa_wq; ws.p[2] = sa_wk; ws.p[3] = sa_wv;
    ws.p[4] = sa_wo; ws.p[5] = ca_wq; ws.p[6] = ca_wk; ws.p[7] = ca_wv;
    ws.p[8] = ca_wo; ws.p[9] = ffn_w1; ws.p[10] = ffn_w2; ws.p[11] = x;
    wconv_kernel<<<6400, 256, 0, stream>>>(ws, wsb);

    // 1. window |max-min|+eps, transposed bf16: res_tb [b][n][c]
    win_kernel<<<4096, 256, 0, stream>>>(gfeat, res_tb, 4 * 512 * 512);

    // 2. conv+relu: crossb[b][o][n]
    bgemm_kernel<2, 1, false, 1><<<dim3(8, 8, 4), 256, 0, stream>>>(
        conv_wb, res_tb, conv_b, nullptr, crossb, 512, 512, 512, 0, 262144, 262144,
        nullptr, nullptr, nullptr, nullptr, 0);

    // 3. fused self-attn QKV projection: N=1536 -> qb (scaled), kb, vtb (transposed)
    bgemm_kernel<1, 0, false, 3><<<dim3(64, 24), 256, 0, stream>>>(
        xb, sa_wqb, sa_bq, nullptr, qb, 4096, 1536, 512, 0, 0, 0,
        kb, vtb, sa_bk, sa_bv, 10);

    // 4. self attention (S=1024) -> attb bf16
    attn_mfma_kernel<<<dim3(64, 16), 256, 0, stream>>>(qb, kb, vtb, attb, 1024, 1024);

    // 5. out proj + resid x -> h fp32
    bgemm_kernel<1, 0, true, 0><<<dim3(64, 8), 256, 0, stream>>>(
        attb, sa_wob, sa_bo, x, h, 4096, 512, 512, 0, 0, 0,
        nullptr, nullptr, nullptr, nullptr, 0);

    // 6. LN1 -> hn fp32 + hnb bf16
    ln_kernel<false, true><<<4096, 256, 0, stream>>>(h, n1_g, n1_b, hn, hnb);

    // 7. cross-attn: Q proj (scaled), fused K2/V2 proj
    bgemm_kernel<1, 3, false, 1><<<dim3(64, 8), 256, 0, stream>>>(
        hnb, ca_wqb, ca_bq, nullptr, qb, 4096, 512, 512, 0, 0, 0,
        nullptr, nullptr, nullptr, nullptr, 0);
    bgemm_kernel<1, 0, false, 4><<<dim3(32, 16), 256, 0, stream>>>(
        crossb, ca_wkb, ca_bk, nullptr, k2b, 2048, 1024, 512, 0, 0, 0,
        nullptr, v2tb, ca_bv, nullptr, 9);

    // 8. cross attention (S=512) -> attb bf16
    attn_mfma_kernel<<<dim3(64, 16), 256, 0, stream>>>(qb, k2b, v2tb, attb, 1024, 512);

    // 9. out proj + resid hn -> h fp32
    bgemm_kernel<1, 0, true, 0><<<dim3(64, 8), 256, 0, stream>>>(
        attb, ca_wob, ca_bo, hn, h, 4096, 512, 512, 0, 0, 0,
        nullptr, nullptr, nullptr, nullptr, 0);

    // 10. LN2 -> hn fp32 + hnb bf16
    ln_kernel<false, true><<<4096, 256, 0, stream>>>(h, n2_g, n2_b, hn, hnb);

    // 11. FFN up + exact gelu -> midb bf16  [4096,2048]
    bgemm_kernel<1, 2, false, 1><<<dim3(64, 32), 256, 0, stream>>>(
        hnb, ffn1b, ffn_b1, nullptr, midb, 4096, 2048, 512, 0, 0, 0,
        nullptr, nullptr, nullptr, nullptr, 0);

    // 12. FFN down + resid hn -> h fp32  [4096,512] K=2048
    bgemm_kernel<1, 0, true, 0><<<dim3(64, 8), 256, 0, stream>>>(
        midb, ffn2b, ffn_b2, hn, h, 4096, 512, 2048, 0, 0, 0,
        nullptr, nullptr, nullptr, nullptr, 0);

    // 13. LN3 + transpose -> d_out [B,512,L] fp32
    ln_kernel<true, false><<<4096, 256, 0, stream>>>(h, n3_g, n3_b, (float*)d_out, nullptr);
}

// Round 6
// 193.158 us; speedup vs baseline: 7.7110x; 1.2930x over previous
//
#include <hip/hip_runtime.h>
#include <hip/hip_bf16.h>
#include <math.h>

#define SCALE_ATTN 0.17677669529663687f  // 1/sqrt(32)
#define SCALE_Q 0.25504522f              // 1/sqrt(32) * log2(e)  (Q pre-scale for exp2 softmax)

typedef unsigned short u16;
typedef unsigned int u32;
typedef __attribute__((ext_vector_type(8))) short bshort8;
typedef __attribute__((ext_vector_type(4))) short sshort4;
typedef __attribute__((ext_vector_type(4))) float f32x4;
typedef __attribute__((ext_vector_type(4))) u32 u32x4;

__device__ inline u16 f2b(float f) {  // fp32 -> bf16 RNE
    union { float f; uint32_t u; } c;
    c.f = f;
    uint32_t u = c.u;
    return (u16)((u + 0x7fffu + ((u >> 16) & 1u)) >> 16);
}

__device__ __forceinline__ u32 cvtpk(float a, float b) {  // {lo=bf16(a), hi=bf16(b)}
    u32 r;
    asm("v_cvt_pk_bf16_f32 %0, %1, %2" : "=v"(r) : "v"(a), "v"(b));
    return r;
}

__device__ __forceinline__ float exp2c(float s) {  // 2^min(s,100)
    float c = fminf(s, 100.f);
    float r;
    asm("v_exp_f32 %0, %1" : "=v"(r) : "v"(c));
    return r;
}

__device__ inline void gload_lds16(const void* g, void* lds) {
    __builtin_amdgcn_global_load_lds(
        (const __attribute__((address_space(1))) void*)g,
        (__attribute__((address_space(3))) void*)lds, 16, 0, 0);
}

// ---------------- batched fp32->bf16 convert (11 weights + x) ----------------
struct WSrc { const float* p[12]; };
__global__ __launch_bounds__(256) void wconv_kernel(WSrc s, u16* __restrict__ dst) {
    long e = ((long)blockIdx.x * 256 + threadIdx.x) * 4;
    if (e >= 6553600) return;
    int w; long base;
    if (e < 2359296)      { w = (int)(e >> 18); base = (long)w << 18; }
    else if (e < 3407872) { w = 9;  base = 2359296; }
    else if (e < 4456448) { w = 10; base = 3407872; }
    else                  { w = 11; base = 4456448; }
    float4 v = *(const float4*)(s.p[w] + (e - base));
    dst[e + 0] = f2b(v.x); dst[e + 1] = f2b(v.y);
    dst[e + 2] = f2b(v.z); dst[e + 3] = f2b(v.w);
}

// ---------------- window |max-min| + eps -> transposed bf16 [b][n][c] ----------------
__global__ __launch_bounds__(256) void win_kernel(const float* __restrict__ G,
                                                  u16* __restrict__ Rt, int total) {
    int i = blockIdx.x * 256 + threadIdx.x;
    if (i >= total) return;
    const float4* p = reinterpret_cast<const float4*>(G) + (size_t)i * 2;
    float4 a = p[0], b = p[1];
    float mx = fmaxf(fmaxf(fmaxf(a.x, a.y), fmaxf(a.z, a.w)),
                     fmaxf(fmaxf(b.x, b.y), fmaxf(b.z, b.w)));
    float mn = fminf(fminf(fminf(a.x, a.y), fminf(a.z, a.w)),
                     fminf(fminf(b.x, b.y), fminf(b.z, b.w)));
    int b_ = i >> 18, c = (i >> 9) & 511, n = i & 511;
    Rt[((long)(b_ * 512 + n) << 9) + c] = f2b(fabsf(mx - mn) + 1e-6f);
}

// ---------------- bf16 MFMA GEMM ----------------
// C[m,n] = act(sum_k A[m,k]*Bt[n,k] + bias) (+resid). 64x64 tile, BK=64, 4 waves.
// BIASMODE: 0 none, 1 per-n, 2 per-m. ACT: 0 none, 1 relu, 2 gelu, 3 *SCALE_Q.
// OUTMODE: 0 fp32, 1 bf16, 2 bf16 batch-transposed (lbits),
//          3 fused QKV split (Cout=q *SCALE_Q, D1=k, D2=v transposed lbits=10),
//          4 fused KV split (Cout=k2, D2=v2 transposed lbits=9).
template <int BIASMODE, int ACT, bool RESID, int OUTMODE>
__global__ __launch_bounds__(256) void bgemm_kernel(
    const u16* __restrict__ A, const u16* __restrict__ Bt,
    const float* __restrict__ bias, const float* __restrict__ Rres,
    void* __restrict__ Cout, int M, int N, int K,
    long sA, long sB, long sC,
    u16* __restrict__ D1, u16* __restrict__ D2,
    const float* __restrict__ bias1, const float* __restrict__ bias2, int lbits) {
    A  += (long)blockIdx.z * sA;
    Bt += (long)blockIdx.z * sB;
    __shared__ u16 As[64 * 64];
    __shared__ u16 Bs[64 * 64];
    int tid = threadIdx.x;
    int lane = tid & 63, wv = tid >> 6;
    int wr = wv >> 1, wc = wv & 1;
    int m0 = blockIdx.x * 64, n0 = blockIdx.y * 64;
    f32x4 acc[2][2] = {};
    int srow = lane >> 3;
    int sbo = ((lane & 7) << 4) ^ (srow << 4);
    int selem = sbo >> 1;
    for (int k0 = 0; k0 < K; k0 += 64) {
        #pragma unroll
        for (int i = 0; i < 2; i++) {
            int r = i * 32 + wv * 8 + srow;
            gload_lds16(A + (long)(m0 + r) * K + k0 + selem,
                        (char*)As + (i * 32 + wv * 8) * 128);
            gload_lds16(Bt + (long)(n0 + r) * K + k0 + selem,
                        (char*)Bs + (i * 32 + wv * 8) * 128);
        }
        __syncthreads();
        #pragma unroll
        for (int ks = 0; ks < 2; ks++) {
            bshort8 af[2], bf[2];
            int kbo = ks * 64 + ((lane >> 4) << 4);
            #pragma unroll
            for (int f = 0; f < 2; f++) {
                int arow = wr * 32 + f * 16 + (lane & 15);
                af[f] = *(const bshort8*)((const char*)As + arow * 128 +
                                          (kbo ^ ((arow & 7) << 4)));
                int brow = wc * 32 + f * 16 + (lane & 15);
                bf[f] = *(const bshort8*)((const char*)Bs + brow * 128 +
                                          (kbo ^ ((brow & 7) << 4)));
            }
            #pragma unroll
            for (int fi = 0; fi < 2; fi++)
                #pragma unroll
                for (int fj = 0; fj < 2; fj++)
                    acc[fi][fj] = __builtin_amdgcn_mfma_f32_16x16x32_bf16(
                        af[fi], bf[fj], acc[fi][fj], 0, 0, 0);
        }
        __syncthreads();
    }
    #pragma unroll
    for (int fi = 0; fi < 2; fi++)
        #pragma unroll
        for (int fj = 0; fj < 2; fj++)
            #pragma unroll
            for (int r = 0; r < 4; r++) {
                int row = m0 + wr * 32 + fi * 16 + ((lane >> 4) << 2) + r;
                int col = n0 + wc * 32 + fj * 16 + (lane & 15);
                float v = acc[fi][fj][r];
                if (OUTMODE == 3) {
                    int grp = col >> 9, c = col & 511;
                    float bb = (grp == 0) ? bias[c] : (grp == 1) ? bias1[c] : bias2[c];
                    float vv = v + bb;
                    if (grp == 0)
                        ((u16*)Cout)[(long)row * 512 + c] = f2b(vv * SCALE_Q);
                    else if (grp == 1)
                        D1[(long)row * 512 + c] = f2b(vv);
                    else
                        D2[((long)((row >> 10) * 512 + c) << 10) + (row & 1023)] = f2b(vv);
                } else if (OUTMODE == 4) {
                    int grp = col >> 9, c = col & 511;
                    float vv = v + ((grp == 0) ? bias[c] : bias1[c]);
                    if (grp == 0)
                        ((u16*)Cout)[(long)row * 512 + c] = f2b(vv);
                    else
                        D2[((long)((row >> 9) * 512 + c) << 9) + (row & 511)] = f2b(vv);
                } else {
                    if (BIASMODE == 1) v += bias[col];
                    if (BIASMODE == 2) v += bias[row];
                    if (ACT == 1) v = fmaxf(v, 0.f);
                    if (ACT == 2) v = 0.5f * v * (1.f + erff(v * 0.70710678118654752f));
                    if (ACT == 3) v *= SCALE_Q;
                    if (RESID) v += Rres[(long)row * N + col];
                    if (OUTMODE == 2) {
                        int rl = row & ((1 << lbits) - 1);
                        long off = ((long)(row >> lbits) * N + col) << lbits;
                        ((u16*)Cout)[off + rl] = f2b(v);
                    } else {
                        long off = (long)blockIdx.z * sC + (long)row * N + col;
                        if (OUTMODE == 1) ((u16*)Cout)[off] = f2b(v);
                        else              ((float*)Cout)[off] = v;
                    }
                }
            }
}

// ---------------- fused MFMA flash attention, LDS-staged, no-max exp2 softmax -------
// Q [B,L,512] bf16 (pre-scaled by 1/sqrt(32)*log2e), K [B,S,512] bf16,
// Vt [B,512,S] bf16, O [B,L,512] bf16.
// Grid (bh=64, L/64), 4 waves; block owns 64 queries of one (b,h); all waves
// cooperatively double-buffer K(64x32)/V^T(32x64) tiles in LDS via
// global_load_lds with counted vmcnt (tile t+1 in flight across the barrier).
// Softmax: unshifted — P = exp2(score'), score' pre-scaled by log2e; clamp 100.
__global__ __launch_bounds__(256) void attn_mfma_kernel(
    const u16* __restrict__ Q, const u16* __restrict__ K,
    const u16* __restrict__ Vt, u16* __restrict__ O, int L, int S) {
    __shared__ __align__(16) u16 Ks[2][2048];  // [64 keys][32 d]
    __shared__ __align__(16) u16 Vs[2][2048];  // [32 d][64 keys]
    int bh = blockIdx.x;
    int b = bh >> 4, h = bh & 15;
    int tid = threadIdx.x;
    int lane = tid & 63, wv = tid >> 6;
    int q0 = blockIdx.y * 64 + wv * 16;
    int qr = lane & 15, g = lane >> 4, g8 = g * 8;
    int kperm = 8 * (qr >> 2) + (qr & 3);

    const u16* Kb = K + (long)b * S * 512 + h * 32;
    const u16* Vb = Vt + ((long)b * 512 + h * 32) * S;
    bshort8 qf = *(const bshort8*)(Q + ((long)(b * L + q0 + qr)) * 512 + h * 32 + g8);

    // staging: wave wv stages K rows 16wv..16wv+15 (64B each) and V rows 8wv..8wv+7 (128B)
    const u16* ksrc = Kb + (long)(wv * 16 + (lane >> 2)) * 512 + ((lane & 3) << 3);
    const u16* vsrc = Vb + (long)(wv * 8 + (lane >> 3)) * S + ((lane & 7) << 3);

    f32x4 acc0 = {}, acc1 = {};
    float lsum = 0.f;

    int nt = S >> 6;
    // prologue: stage tile 0
    gload_lds16(ksrc, (char*)Ks[0] + wv * 1024);
    gload_lds16(vsrc, (char*)Vs[0] + wv * 1024);
    int cur = 0;
    for (int t = 0; t < nt; ++t) {
        if (t + 1 < nt) {
            int s0 = (t + 1) << 6;
            gload_lds16(ksrc + (long)s0 * 512, (char*)Ks[cur ^ 1] + wv * 1024);
            gload_lds16(vsrc + s0, (char*)Vs[cur ^ 1] + wv * 1024);
            asm volatile("s_waitcnt vmcnt(2)\ns_barrier" ::: "memory");
        } else {
            asm volatile("s_waitcnt vmcnt(0)\ns_barrier" ::: "memory");
        }
        const u16* Kt = Ks[cur];
        const u16* Vl = Vs[cur];
        bshort8 a0 = *(const bshort8*)(Kt + kperm * 32 + g8);
        bshort8 a1 = *(const bshort8*)(Kt + (kperm + 4) * 32 + g8);
        bshort8 a2 = *(const bshort8*)(Kt + (kperm + 32) * 32 + g8);
        bshort8 a3 = *(const bshort8*)(Kt + (kperm + 36) * 32 + g8);
        bshort8 v00 = *(const bshort8*)(Vl + qr * 64 + g8);
        bshort8 v01 = *(const bshort8*)(Vl + qr * 64 + 32 + g8);
        bshort8 v10 = *(const bshort8*)(Vl + (16 + qr) * 64 + g8);
        bshort8 v11 = *(const bshort8*)(Vl + (16 + qr) * 64 + 32 + g8);
        f32x4 z = {0.f, 0.f, 0.f, 0.f};
        f32x4 st0 = __builtin_amdgcn_mfma_f32_16x16x32_bf16(a0, qf, z, 0, 0, 0);
        f32x4 st1 = __builtin_amdgcn_mfma_f32_16x16x32_bf16(a1, qf, z, 0, 0, 0);
        f32x4 st2 = __builtin_amdgcn_mfma_f32_16x16x32_bf16(a2, qf, z, 0, 0, 0);
        f32x4 st3 = __builtin_amdgcn_mfma_f32_16x16x32_bf16(a3, qf, z, 0, 0, 0);
        float p0[4], p1[4], p2[4], p3[4];
        #pragma unroll
        for (int r = 0; r < 4; r++) {
            p0[r] = exp2c(st0[r]);
            p1[r] = exp2c(st1[r]);
            p2[r] = exp2c(st2[r]);
            p3[r] = exp2c(st3[r]);
        }
        float ps = ((p0[0] + p0[1]) + (p0[2] + p0[3])) + ((p1[0] + p1[1]) + (p1[2] + p1[3])) +
                   ((p2[0] + p2[1]) + (p2[2] + p2[3])) + ((p3[0] + p3[1]) + (p3[2] + p3[3]));
        lsum += ps;
        u32x4 P0 = { cvtpk(p0[0], p0[1]), cvtpk(p0[2], p0[3]),
                     cvtpk(p1[0], p1[1]), cvtpk(p1[2], p1[3]) };
        u32x4 P1 = { cvtpk(p2[0], p2[1]), cvtpk(p2[2], p2[3]),
                     cvtpk(p3[0], p3[1]), cvtpk(p3[2], p3[3]) };
        bshort8 pf0 = *(bshort8*)&P0;
        bshort8 pf1 = *(bshort8*)&P1;
        acc0 = __builtin_amdgcn_mfma_f32_16x16x32_bf16(v00, pf0, acc0, 0, 0, 0);
        acc0 = __builtin_amdgcn_mfma_f32_16x16x32_bf16(v01, pf1, acc0, 0, 0, 0);
        acc1 = __builtin_amdgcn_mfma_f32_16x16x32_bf16(v10, pf0, acc1, 0, 0, 0);
        acc1 = __builtin_amdgcn_mfma_f32_16x16x32_bf16(v11, pf1, acc1, 0, 0, 0);
        asm volatile("s_barrier" ::: "memory");
        cur ^= 1;
    }

    lsum += __shfl_xor(lsum, 16);
    lsum += __shfl_xor(lsum, 32);
    float inv = 1.f / lsum;
    u16* op = O + ((long)(b * L + q0 + qr)) * 512 + h * 32 + g * 4;
    sshort4 o0, o1;
    #pragma unroll
    for (int r = 0; r < 4; r++) {
        o0[r] = (short)f2b(acc0[r] * inv);
        o1[r] = (short)f2b(acc1[r] * inv);
    }
    *(sshort4*)op = o0;
    *(sshort4*)(op + 16) = o1;
}

// ---------------- layernorm over 512; optional bf16 dual-store / transposed out ------
template <bool TRANS, bool DUAL>
__global__ __launch_bounds__(256) void ln_kernel(const float* __restrict__ X,
                                                 const float* __restrict__ g,
                                                 const float* __restrict__ bt,
                                                 float* __restrict__ Y,
                                                 u16* __restrict__ Yb) {
    int row = blockIdx.x;
    const float* xr = X + (long)row * 512;
    int t = threadIdx.x;
    float x0 = xr[t], x1 = xr[t + 256];
    float s = x0 + x1, ss = x0 * x0 + x1 * x1;
    #pragma unroll
    for (int off = 32; off > 0; off >>= 1) {
        s += __shfl_down(s, off);
        ss += __shfl_down(ss, off);
    }
    __shared__ float sred[4], ssred[4];
    int wid = t >> 6;
    if ((t & 63) == 0) { sred[wid] = s; ssred[wid] = ss; }
    __syncthreads();
    float ts = sred[0] + sred[1] + sred[2] + sred[3];
    float tss = ssred[0] + ssred[1] + ssred[2] + ssred[3];
    float mean = ts * (1.f / 512.f);
    float var = tss * (1.f / 512.f) - mean * mean;
    float rstd = rsqrtf(var + 1e-5f);
    float y0 = (x0 - mean) * rstd * g[t] + bt[t];
    float y1 = (x1 - mean) * rstd * g[t + 256] + bt[t + 256];
    if (TRANS) {
        int b = row >> 10, l = row & 1023;
        Y[((long)b * 512 + t) * 1024 + l] = y0;
        Y[((long)b * 512 + t + 256) * 1024 + l] = y1;
    } else {
        Y[(long)row * 512 + t] = y0;
        Y[(long)row * 512 + t + 256] = y1;
    }
    if (DUAL) {
        Yb[(long)row * 512 + t] = f2b(y0);
        Yb[(long)row * 512 + t + 256] = f2b(y1);
    }
}

extern "C" void kernel_launch(void* const* d_in, const int* in_sizes, int n_in,
                              void* d_out, int out_size, void* d_ws, size_t ws_size,
                              hipStream_t stream) {
    const float* x      = (const float*)d_in[0];
    const float* gfeat  = (const float*)d_in[1];
    const float* conv_w = (const float*)d_in[2];
    const float* conv_b = (const float*)d_in[3];
    const float* sa_wq = (const float*)d_in[4];
    const float* sa_bq = (const float*)d_in[5];
    const float* sa_wk = (const float*)d_in[6];
    const float* sa_bk = (const float*)d_in[7];
    const float* sa_wv = (const float*)d_in[8];
    const float* sa_bv = (const float*)d_in[9];
    const float* sa_wo = (const float*)d_in[10];
    const float* sa_bo = (const float*)d_in[11];
    const float* ca_wq = (const float*)d_in[12];
    const float* ca_bq = (const float*)d_in[13];
    const float* ca_wk = (const float*)d_in[14];
    const float* ca_bk = (const float*)d_in[15];
    const float* ca_wv = (const float*)d_in[16];
    const float* ca_bv = (const float*)d_in[17];
    const float* ca_wo = (const float*)d_in[18];
    const float* ca_bo = (const float*)d_in[19];
    const float* ffn_w1 = (const float*)d_in[20];
    const float* ffn_b1 = (const float*)d_in[21];
    const float* ffn_w2 = (const float*)d_in[22];
    const float* ffn_b2 = (const float*)d_in[23];
    const float* n1_g = (const float*)d_in[24];
    const float* n1_b = (const float*)d_in[25];
    const float* n2_g = (const float*)d_in[26];
    const float* n2_b = (const float*)d_in[27];
    const float* n3_g = (const float*)d_in[28];
    const float* n3_b = (const float*)d_in[29];
    (void)ws_size; (void)n_in; (void)in_sizes; (void)out_size;

    const long M_ = 1048576;
    float* W0 = (float*)d_ws;
    float* h   = W0;                 // [0, 2M) fp32
    float* hn  = W0 + 2 * M_;        // [2M, 4M) fp32
    u16* U = (u16*)(W0 + 4 * M_);
    u16* qb     = U;                 // 2M u16
    u16* kb     = U + 2 * M_;        // 2M
    u16* vtb    = U + 4 * M_;        // 2M   [4][512][1024]
    u16* k2b    = U + 6 * M_;        // 1M
    u16* v2tb   = U + 7 * M_;        // 1M   [4][512][512]
    u16* attb   = U + 8 * M_;        // 2M
    u16* hnb    = U + 10 * M_;       // 2M
    u16* midb   = U + 12 * M_;       // 8M
    u16* wsb    = U + 20 * M_;       // 6.55M
    u16* res_tb = U + 27 * M_;       // 1M
    u16* crossb = U + 28 * M_;       // 1M

    const u16* conv_wb = wsb;
    const u16* sa_wqb = wsb + 262144;   // wq,wk,wv contiguous -> fused QKV weight
    const u16* sa_wob = wsb + 1048576;
    const u16* ca_wqb = wsb + 1310720;
    const u16* ca_wkb = wsb + 1572864;  // wk,wv contiguous -> fused KV weight
    const u16* ca_wob = wsb + 2097152;
    const u16* ffn1b = wsb + 2359296, *ffn2b = wsb + 3407872;
    const u16* xb = wsb + 4456448;

    // 0. convert weights + x to bf16
    WSrc ws;
    ws.p[0] = conv_w; ws.p[1] = sa_wq; ws.p[2] = sa_wk; ws.p[3] = sa_wv;
    ws.p[4] = sa_wo; ws.p[5] = ca_wq; ws.p[6] = ca_wk; ws.p[7] = ca_wv;
    ws.p[8] = ca_wo; ws.p[9] = ffn_w1; ws.p[10] = ffn_w2; ws.p[11] = x;
    wconv_kernel<<<6400, 256, 0, stream>>>(ws, wsb);

    // 1. window |max-min|+eps, transposed bf16: res_tb [b][n][c]
    win_kernel<<<4096, 256, 0, stream>>>(gfeat, res_tb, 4 * 512 * 512);

    // 2. conv+relu: crossb[b][o][n]
    bgemm_kernel<2, 1, false, 1><<<dim3(8, 8, 4), 256, 0, stream>>>(
        conv_wb, res_tb, conv_b, nullptr, crossb, 512, 512, 512, 0, 262144, 262144,
        nullptr, nullptr, nullptr, nullptr, 0);

    // 3. fused self-attn QKV projection: N=1536 -> qb (scaled), kb, vtb (transposed)
    bgemm_kernel<1, 0, false, 3><<<dim3(64, 24), 256, 0, stream>>>(
        xb, sa_wqb, sa_bq, nullptr, qb, 4096, 1536, 512, 0, 0, 0,
        kb, vtb, sa_bk, sa_bv, 10);

    // 4. self attention (S=1024) -> attb bf16
    attn_mfma_kernel<<<dim3(64, 16), 256, 0, stream>>>(qb, kb, vtb, attb, 1024, 1024);

    // 5. out proj + resid x -> h fp32
    bgemm_kernel<1, 0, true, 0><<<dim3(64, 8), 256, 0, stream>>>(
        attb, sa_wob, sa_bo, x, h, 4096, 512, 512, 0, 0, 0,
        nullptr, nullptr, nullptr, nullptr, 0);

    // 6. LN1 -> hn fp32 + hnb bf16
    ln_kernel<false, true><<<4096, 256, 0, stream>>>(h, n1_g, n1_b, hn, hnb);

    // 7. cross-attn: Q proj (scaled), fused K2/V2 proj
    bgemm_kernel<1, 3, false, 1><<<dim3(64, 8), 256, 0, stream>>>(
        hnb, ca_wqb, ca_bq, nullptr, qb, 4096, 512, 512, 0, 0, 0,
        nullptr, nullptr, nullptr, nullptr, 0);
    bgemm_kernel<1, 0, false, 4><<<dim3(32, 16), 256, 0, stream>>>(
        crossb, ca_wkb, ca_bk, nullptr, k2b, 2048, 1024, 512, 0, 0, 0,
        nullptr, v2tb, ca_bv, nullptr, 9);

    // 8. cross attention (S=512) -> attb bf16
    attn_mfma_kernel<<<dim3(64, 16), 256, 0, stream>>>(qb, k2b, v2tb, attb, 1024, 512);

    // 9. out proj + resid hn -> h fp32
    bgemm_kernel<1, 0, true, 0><<<dim3(64, 8), 256, 0, stream>>>(
        attb, ca_wob, ca_bo, hn, h, 4096, 512, 512, 0, 0, 0,
        nullptr, nullptr, nullptr, nullptr, 0);

    // 10. LN2 -> hn fp32 + hnb bf16
    ln_kernel<false, true><<<4096, 256, 0, stream>>>(h, n2_g, n2_b, hn, hnb);

    // 11. FFN up + exact gelu -> midb bf16  [4096,2048]
    bgemm_kernel<1, 2, false, 1><<<dim3(64, 32), 256, 0, stream>>>(
        hnb, ffn1b, ffn_b1, nullptr, midb, 4096, 2048, 512, 0, 0, 0,
        nullptr, nullptr, nullptr, nullptr, 0);

    // 12. FFN down + resid hn -> h fp32  [4096,512] K=2048
    bgemm_kernel<1, 0, true, 0><<<dim3(64, 8), 256, 0, stream>>>(
        midb, ffn2b, ffn_b2, hn, h, 4096, 512, 2048, 0, 0, 0,
        nullptr, nullptr, nullptr, nullptr, 0);

    // 13. LN3 + transpose -> d_out [B,512,L] fp32
    ln_kernel<true, false><<<4096, 256, 0, stream>>>(h, n3_g, n3_b, (float*)d_out, nullptr);
}